// Round 11
// baseline (288.722 us; speedup 1.0000x reference)
//
#include <hip/hip_runtime.h>
#include <hip/hip_bf16.h>
#include <hip/hip_fp16.h>

// SplineCNN forward, MI355X round 11.
// R10 -> R11: pass2 (both layers read the full 102MB msg stream) was still
// top: NT loads blocked L1/L2 allocation, clamp+mask burned ~10 VALU/load,
// root-GEMV was a 64-deep serial fmaf chain. Now: cached loads, clamp-free
// full iterations + one masked tail, 4-way GEMV ILP. Launcher: srcS pad
// sentinels written by scan_fused (kills a 3.2MB memset), degi+fill2 merged
// into one memset.

typedef __attribute__((ext_vector_type(8))) _Float16 f16x8;
typedef __attribute__((ext_vector_type(4))) _Float16 f16x4;
typedef __attribute__((ext_vector_type(4))) float f32x4;

constexpr int NN = 50000;       // nodes
constexpr int EE = 800000;      // edges
constexpr int CHUNK = 256;      // edges per block in edge_mfma
constexpr int EB = EE / 256;    // 3125 prep/scatter blocks
static_assert(EE % 256 == 0, "prep grid assumes exact divisibility");
constexpr int ELIST_LEN = EE + 16 * CHUNK;
constexpr int NBLK_EDGE = ELIST_LEN / CHUNK;   // 3141

// ---------------------------------------------------------------- dtype probe
__global__ void detect_i64(const long long* __restrict__ eidx, int* __restrict__ flag) {
  long long v = eidx[threadIdx.x];
  bool ok = (v >= 0) && (v < (long long)NN);
  unsigned long long m = __ballot(ok);
  if (threadIdx.x == 0) flag[0] = (m == ~0ull) ? 1 : 0;
}

// ------------------------------------------------------------------- prep
__global__ __launch_bounds__(256) void prep_edges(
    const void* __restrict__ eidx, const float* __restrict__ attr,
    const int* __restrict__ flag,
    int* __restrict__ src, int* __restrict__ dst,
    int* __restrict__ degi, int* __restrict__ bhT) {
  __shared__ int wc[4][16];
  const int tid = threadIdx.x;
  const int e = blockIdx.x * 256 + tid;
  int s, d;
  if (flag[0]) {
    s = (int)((const long long*)eidx)[e];
    d = (int)((const long long*)eidx)[EE + e];
  } else {
    s = ((const int*)eidx)[e];
    d = ((const int*)eidx)[EE + e];
  }
  src[e] = s;
  dst[e] = d;
  atomicAdd(&degi[d], 1);
  const float v0 = attr[2 * e] * 4.0f, v1 = attr[2 * e + 1] * 4.0f;
  const int bx = min(max((int)floorf(v0), 0), 3);
  const int by = min(max((int)floorf(v1), 0), 3);
  const int c = bx + 4 * by;
  const int wave = tid >> 6, lane = tid & 63;
#pragma unroll
  for (int k = 0; k < 16; ++k) {
    unsigned long long mm = __ballot(c == k);
    if (lane == k) wc[wave][k] = __popcll(mm);
  }
  __syncthreads();
  if (tid < 16)
    bhT[tid * EB + blockIdx.x] = wc[0][tid] + wc[1][tid] + wc[2][tid] + wc[3][tid];
}

// --------------------------------------------------------------- fused scans
// Block 0 additionally writes -1 sentinels into srcS's per-cell pad slots
// (replaces a 3.2MB whole-array memset).
__global__ __launch_bounds__(1024) void scan_fused(
    const int* __restrict__ bhT, int* __restrict__ blkbaseT,
    int* __restrict__ chunkcell, int* __restrict__ srcS,
    const int* __restrict__ degi, int* __restrict__ dstbase) {
  const int wave = threadIdx.x >> 6, lane = threadIdx.x & 63;
  if (blockIdx.x == 0) {
    constexpr int CH = (EB + 63) / 64;   // 49
    __shared__ int ofs_s[16];
    __shared__ int tot_s[16];
    int v[CH];
#pragma unroll
    for (int ch = 0; ch < CH; ++ch) {
      const int b = ch * 64 + lane;
      v[ch] = (b < EB) ? bhT[wave * EB + b] : 0;
    }
    {
      int sum = 0;
#pragma unroll
      for (int ch = 0; ch < CH; ++ch) sum += v[ch];
#pragma unroll
      for (int off = 32; off > 0; off >>= 1) sum += __shfl_down(sum, off);
      if (lane == 0) tot_s[wave] = sum;
    }
    __syncthreads();
    if (threadIdx.x == 0) {
      int t = 0;
      for (int c = 0; c < 16; ++c) {
        ofs_s[c] = t;
        t += ((tot_s[c] + CHUNK - 1) / CHUNK) * CHUNK;
      }
    }
    __syncthreads();
    {  // chunk -> cell map; padding chunks get -1
      const int nch = (tot_s[wave] + CHUNK - 1) / CHUNK;
      const int cb = ofs_s[wave] / CHUNK;
      for (int i = lane; i < nch; i += 64) chunkcell[cb + i] = wave;
      if (wave == 15) {
        const int totch = cb + nch;
        for (int i = totch + lane; i < NBLK_EDGE; i += 64) chunkcell[i] = -1;
      }
    }
    {  // srcS pad sentinels for this cell's segment
      const int startp = ofs_s[wave] + tot_s[wave];
      const int endp = ofs_s[wave] + ((tot_s[wave] + CHUNK - 1) / CHUNK) * CHUNK;
      for (int p = startp + lane; p < endp; p += 64) srcS[p] = -1;
    }
    int running = ofs_s[wave];
#pragma unroll
    for (int ch = 0; ch < CH; ++ch) {
      int inc = v[ch];
#pragma unroll
      for (int off = 1; off < 64; off <<= 1) {
        int n = __shfl_up(inc, off);
        if (lane >= off) inc += n;
      }
      const int b = ch * 64 + lane;
      if (b < EB) blkbaseT[wave * EB + b] = running + inc - v[ch];
      running += __shfl(inc, 63);
    }
  } else {
    constexpr int SEG = NN / 16;          // 3125
    constexpr int CH = (SEG + 63) / 64;   // 49
    __shared__ int wofs[16];
    const int nbase = wave * SEG;
    int v[CH];
#pragma unroll
    for (int ch = 0; ch < CH; ++ch) {
      const int i = ch * 64 + lane;
      v[ch] = (i < SEG) ? degi[nbase + i] : 0;
    }
    {
      int sum = 0;
#pragma unroll
      for (int ch = 0; ch < CH; ++ch) sum += v[ch];
#pragma unroll
      for (int off = 32; off > 0; off >>= 1) sum += __shfl_down(sum, off);
      if (lane == 0) wofs[wave] = sum;
    }
    __syncthreads();
    if (threadIdx.x == 0) {
      int t = 0;
      for (int w2 = 0; w2 < 16; ++w2) { int tv = wofs[w2]; wofs[w2] = t; t += tv; }
    }
    __syncthreads();
    int running = wofs[wave];
#pragma unroll
    for (int ch = 0; ch < CH; ++ch) {
      int inc = v[ch];
#pragma unroll
      for (int off = 1; off < 64; off <<= 1) {
        int n = __shfl_up(inc, off);
        if (lane >= off) inc += n;
      }
      const int i = ch * 64 + lane;
      if (i < SEG) dstbase[nbase + i] = running + inc - v[ch];
      running += __shfl(inc, 63);
    }
  }
}

// Deterministic cell-sorted scatter; recomputes cell+basis from attr.
__global__ __launch_bounds__(256) void scatter_edges(
    const float* __restrict__ attr, const int* __restrict__ blkbaseT,
    const int* __restrict__ srcArr, const int* __restrict__ dstArr,
    const int* __restrict__ dstbase, int* __restrict__ fill2,
    int* __restrict__ srcS, int* __restrict__ posS, f16x4* __restrict__ basS) {
  __shared__ int wc[4][16];
  __shared__ int bs[4][16];
  const int tid = threadIdx.x;
  const int e = blockIdx.x * 256 + tid;
  const float v0 = attr[2 * e] * 4.0f, v1 = attr[2 * e + 1] * 4.0f;
  const float fl0 = floorf(v0), fl1 = floorf(v1);
  const float fr0 = v0 - fl0, fr1 = v1 - fl1;
  const int bx = min(max((int)fl0, 0), 3);
  const int by = min(max((int)fl1, 0), 3);
  const int c = bx + 4 * by;
  const f16x4 bq = {(_Float16)((1.0f - fr0) * (1.0f - fr1)),
                    (_Float16)(fr0 * (1.0f - fr1)),
                    (_Float16)((1.0f - fr0) * fr1),
                    (_Float16)(fr0 * fr1)};
  const int wave = tid >> 6, lane = tid & 63;
  int rank = 0;
#pragma unroll
  for (int k = 0; k < 16; ++k) {
    unsigned long long mm = __ballot(c == k);
    if (k == c) rank = __popcll(mm & ((1ull << lane) - 1ull));
    if (lane == k) wc[wave][k] = __popcll(mm);
  }
  const int d = dstArr[e];
  const int mypos = dstbase[d] + atomicAdd(&fill2[d], 1);
  __syncthreads();
  if (tid < 16) {
    int running = blkbaseT[tid * EB + blockIdx.x];
#pragma unroll
    for (int w = 0; w < 4; ++w) { bs[w][tid] = running; running += wc[w][tid]; }
  }
  __syncthreads();
  const int p = bs[wave][c] + rank;
  srcS[p] = srcArr[e];
  posS[p] = mypos;
  basS[p] = bq;
}

// ------------------------------------------------- fused one-shot converts
constexpr int F2H_LEN8 = NN * 32 / 8;                 // 200000
constexpr int F2H_BLK = (F2H_LEN8 + 255) / 256;       // 782
constexpr int CW32_BLK = 4 * 16;                      // 64
constexpr int CW64_BLK = 8 * 16;                      // 128
constexpr int CFW_BLK = (64 * 160) / 256;             // 40
constexpr int CONV_BLK = F2H_BLK + CW32_BLK + CW64_BLK + CFW_BLK;

template <int IN>
__device__ __forceinline__ void conv_w_body(
    const float* __restrict__ w, _Float16* __restrict__ wcell, int c, int o) {
  constexpr int K = 4 * IN;
  constexpr int RS = K * 2;
  constexpr int OPR = K / 8;
  const int bx = c & 3, by = c >> 2;
  const int n = o / OPR;
  const int k0 = (o - n * OPR) * 8;
  const int ks = k0 >> 5;
  const int g2 = (k0 & 31) >> 3;
  const int s = (IN == 64) ? (ks & 3) : ks;
  const int i0 = ((IN == 64) ? (ks >> 2) * 32 : 0) + g2 * 8;
  const int kk = (bx + (s & 1)) + 5 * (by + (s >> 1));
  const float* wp = w + ((size_t)kk * IN + i0) * 64 + n;
  f16x8 v;
#pragma unroll
  for (int j = 0; j < 8; ++j) v[j] = (_Float16)wp[(size_t)j * 64];
  const int byte = n * RS + ((k0 * 2) ^ ((n & 15) << 4));
  *reinterpret_cast<f16x8*>(
      reinterpret_cast<char*>(wcell) + (size_t)c * (RS * 64) + byte) = v;
}

__global__ __launch_bounds__(256) void convert_all(
    const float* __restrict__ x0, const float* __restrict__ w0,
    const float* __restrict__ w1, const float* __restrict__ fw,
    _Float16* __restrict__ xh0, _Float16* __restrict__ wc0,
    _Float16* __restrict__ wc1, _Float16* __restrict__ fwT) {
  const int b = blockIdx.x, tid = threadIdx.x;
  if (b < F2H_BLK) {
    const int i = b * 256 + tid;
    if (i >= F2H_LEN8) return;
    const float4 a = reinterpret_cast<const float4*>(x0)[i * 2];
    const float4 bb = reinterpret_cast<const float4*>(x0)[i * 2 + 1];
    f16x8 v = {(_Float16)a.x, (_Float16)a.y, (_Float16)a.z, (_Float16)a.w,
               (_Float16)bb.x, (_Float16)bb.y, (_Float16)bb.z, (_Float16)bb.w};
    reinterpret_cast<f16x8*>(xh0)[i] = v;
  } else if (b < F2H_BLK + CW32_BLK) {
    const int r = b - F2H_BLK;
    conv_w_body<32>(w0, wc0, r >> 2, (r & 3) * 256 + tid);
  } else if (b < F2H_BLK + CW32_BLK + CW64_BLK) {
    const int r = b - F2H_BLK - CW32_BLK;
    conv_w_body<64>(w1, wc1, r >> 3, (r & 7) * 256 + tid);
  } else {
    const int i = (b - F2H_BLK - CW32_BLK - CW64_BLK) * 256 + tid;  // < 10240
    const int n = i / 160, k = i - n * 160;
    fwT[i] = (_Float16)fw[k * 64 + n];
  }
}

// ------------------------------------------------------------------- edge msg
template <int IN, bool TWOPASS>
__global__ __launch_bounds__(256) void edge_mfma(
    const _Float16* __restrict__ xh, const _Float16* __restrict__ wcell,
    const int* __restrict__ chunkcell,
    const int* __restrict__ srcS, const int* __restrict__ posS,
    const f16x4* __restrict__ basS,
    _Float16* __restrict__ msg, float* __restrict__ agg) {
  constexpr int K = 4 * IN;
  constexpr int KSTEPS = K / 32;
  constexpr int RS = K * 2;            // LDS row stride bytes
  constexpr int OPR = K / 8;           // 16B chunks per row
  constexpr int TILES = CHUNK / 64;    // 4
  constexpr int NCH = (IN == 64) ? 2 : 1;
  __shared__ f16x8 Wt[64 * OPR];
  const int tid = threadIdx.x;
  const int c = chunkcell[blockIdx.x];
  if (c < 0) return;                   // fully-padded chunk
  const int base = blockIdx.x * CHUNK;
  const int lane = tid & 63;
  const int wave = tid >> 6;
  const int g = lane >> 4, m = lane & 15;
  const int wbase = base + wave * (CHUNK / 4);
  int sv_t[TILES], po_t[TILES];
  f16x4 bas_t[TILES];
#pragma unroll
  for (int t = 0; t < TILES; ++t) sv_t[t] = srcS[wbase + t * 16 + m];
#pragma unroll
  for (int t = 0; t < TILES; ++t) po_t[t] = posS[wbase + t * 16 + m];
#pragma unroll
  for (int t = 0; t < TILES; ++t) bas_t[t] = basS[wbase + t * 16 + m];
  {
    const f16x8* gw = reinterpret_cast<const f16x8*>(wcell) + (size_t)c * (64 * OPR);
    for (int o = tid; o < 64 * OPR; o += 256) Wt[o] = gw[o];
  }
  __syncthreads();
  f16x8 xc[TILES][NCH];
#pragma unroll
  for (int t = 0; t < TILES; ++t) {
    const int row = (sv_t[t] >= 0) ? sv_t[t] : 0;
    const f16x8* xr = reinterpret_cast<const f16x8*>(xh + (size_t)row * IN);
    xc[t][0] = xr[g];
    if constexpr (IN == 64) xc[t][1] = xr[4 + g];
  }
#pragma unroll
  for (int t = 0; t < TILES; ++t) {
    f32x4 acc[4];
#pragma unroll
    for (int nt = 0; nt < 4; ++nt) acc[nt] = (f32x4){0.f, 0.f, 0.f, 0.f};
#pragma unroll
    for (int ks = 0; ks < KSTEPS; ++ks) {
      const int s = (IN == 64) ? (ks & 3) : ks;
      const f16x8 xin = (IN == 64 && (ks >> 2)) ? xc[t][1] : xc[t][0];
      const f16x8 a = xin * bas_t[t][s];
#pragma unroll
      for (int nt = 0; nt < 4; ++nt) {
        const int n = nt * 16 + m;
        const int byte = n * RS + (((ks * 64) + g * 16) ^ ((n & 15) << 4));
        acc[nt] = __builtin_amdgcn_mfma_f32_16x16x32_f16(a, Wt[byte >> 4], acc[nt], 0, 0, 0);
      }
    }
#pragma unroll
    for (int r = 0; r < 4; ++r) {
      const int m2 = g * 4 + r;
      const int er = __shfl(sv_t[t], m2);
      const int pr = __shfl(po_t[t], m2);
      if (er >= 0) {
        if constexpr (TWOPASS) {
          f16x4 pv = {(_Float16)acc[0][r], (_Float16)acc[1][r],
                      (_Float16)acc[2][r], (_Float16)acc[3][r]};
          __builtin_nontemporal_store(
              pv, reinterpret_cast<f16x4*>(msg + (size_t)pr * 64 + m * 4));
        } else {
          float* ap = agg + (size_t)pr * 64 + m;
#pragma unroll
          for (int nt = 0; nt < 4; ++nt) atomicAdd(ap + nt * 16, acc[nt][r]);
        }
      }
    }
  }
}

// --------------------------------------------------------------- pass2
// Segment-reduce + finalize, fp16 state. Cached (non-NT) loads; full 16-row
// iterations with no clamp/mask + one masked tail; 4-way ILP root-GEMV.
template <int IN>
__global__ __launch_bounds__(256) void pass2_kernel(
    const _Float16* __restrict__ msg, const int* __restrict__ dstbase,
    const int* __restrict__ degi, const _Float16* __restrict__ xh_in,
    const float* __restrict__ root, const float* __restrict__ bias,
    _Float16* __restrict__ xh_out) {
  __shared__ float rl[IN * 64];
  __shared__ float xs[4][IN];
  for (int idx = threadIdx.x; idx < IN * 16; idx += 256)
    reinterpret_cast<float4*>(rl)[idx] = reinterpret_cast<const float4*>(root)[idx];
  const int wave = threadIdx.x >> 6, lane = threadIdx.x & 63;
  const int n = blockIdx.x * 4 + wave;   // grid sized so n < NN always
  if (lane < IN / 4) {
    const f16x4 xv = *reinterpret_cast<const f16x4*>(xh_in + (size_t)n * IN + lane * 4);
    float4 xf = {(float)xv[0], (float)xv[1], (float)xv[2], (float)xv[3]};
    reinterpret_cast<float4*>(xs[wave])[lane] = xf;
  }
  __syncthreads();
  const int b0 = dstbase[n], dg = degi[n];
  const int q = lane >> 4, m = lane & 15;
  const _Float16* mp = msg + (size_t)b0 * 64 + m * 4;
  float a0 = 0.f, a1 = 0.f, a2 = 0.f, a3 = 0.f;
  const int nfull = dg & ~15;
  int j0 = 0;
  for (; j0 < nfull; j0 += 16) {
    const _Float16* bp = mp + (size_t)j0 * 64;
#pragma unroll
    for (int u = 0; u < 4; ++u) {
      const f16x4 v = *reinterpret_cast<const f16x4*>(bp + (size_t)(u * 4 + q) * 64);
      a0 += (float)v[0]; a1 += (float)v[1]; a2 += (float)v[2]; a3 += (float)v[3];
    }
  }
  if (j0 < dg) {  // masked tail (<16 rows)
#pragma unroll
    for (int u = 0; u < 4; ++u) {
      const int jj = j0 + u * 4 + q;
      const int jc = min(jj, dg - 1);
      const f16x4 v = *reinterpret_cast<const f16x4*>(mp + (size_t)jc * 64);
      const float wv = (jj < dg) ? 1.0f : 0.0f;
      a0 = fmaf(wv, (float)v[0], a0);
      a1 = fmaf(wv, (float)v[1], a1);
      a2 = fmaf(wv, (float)v[2], a2);
      a3 = fmaf(wv, (float)v[3], a3);
    }
  }
  a0 += __shfl_xor(a0, 16); a0 += __shfl_xor(a0, 32);
  a1 += __shfl_xor(a1, 16); a1 += __shfl_xor(a1, 32);
  a2 += __shfl_xor(a2, 16); a2 += __shfl_xor(a2, 32);
  a3 += __shfl_xor(a3, 16); a3 += __shfl_xor(a3, 32);
  const float acc = (q == 0) ? a0 : (q == 1) ? a1 : (q == 2) ? a2 : a3;
  // root-GEMV with 4 independent chains
  float r0 = acc / fmaxf((float)dg, 1.0f) + bias[lane];
  float r1 = 0.f, r2 = 0.f, r3 = 0.f;
#pragma unroll
  for (int i = 0; i < IN; i += 4) {
    r0 = fmaf(xs[wave][i + 0], rl[(i + 0) * 64 + lane], r0);
    r1 = fmaf(xs[wave][i + 1], rl[(i + 1) * 64 + lane], r1);
    r2 = fmaf(xs[wave][i + 2], rl[(i + 2) * 64 + lane], r2);
    r3 = fmaf(xs[wave][i + 3], rl[(i + 3) * 64 + lane], r3);
  }
  const float r = fmaxf((r0 + r1) + (r2 + r3), 0.0f);
  xh_out[(size_t)n * 64 + lane] = (_Float16)r;
}

// --------------------------------------------------------------- finalize
// (atomic-fallback path only)
template <int IN>
__global__ __launch_bounds__(256) void finalize_kernel(
    const _Float16* __restrict__ xh_in, const float* __restrict__ agg,
    const int* __restrict__ degi, const float* __restrict__ root,
    const float* __restrict__ bias, _Float16* __restrict__ xh_out) {
  __shared__ float rl[IN * 64];
  for (int idx = threadIdx.x; idx < IN * 16; idx += 256)
    reinterpret_cast<float4*>(rl)[idx] = reinterpret_cast<const float4*>(root)[idx];
  __syncthreads();
  const int wave = threadIdx.x >> 6, lane = threadIdx.x & 63;
  const int n = blockIdx.x * 4 + wave;
  if (n >= NN) return;
  const float d = fmaxf((float)degi[n], 1.0f);
  float r = agg[(size_t)n * 64 + lane] / d + bias[lane];
  const _Float16* xr = xh_in + (size_t)n * IN;
#pragma unroll 8
  for (int i = 0; i < IN; ++i) r = fmaf((float)xr[i], rl[i * 64 + lane], r);
  r = fmaxf(r, 0.0f);
  xh_out[(size_t)n * 64 + lane] = (_Float16)r;
}

// ------------------------------------------------------------------- output
__global__ __launch_bounds__(256) void out_mfma(
    const _Float16* __restrict__ xh0, const _Float16* __restrict__ xh1,
    const _Float16* __restrict__ xh2, const _Float16* __restrict__ fwT,
    const float* __restrict__ fb, float* __restrict__ out) {
  const int lane = threadIdx.x & 63, wave = threadIdx.x >> 6;
  const int g = lane >> 4, m = lane & 15;
  const int base = blockIdx.x * 64 + wave * 16;   // NN % 16 == 0
  if (base >= NN) return;
  f16x8 bf[5][4];
#pragma unroll
  for (int ks = 0; ks < 5; ++ks)
#pragma unroll
    for (int nt = 0; nt < 4; ++nt)
      bf[ks][nt] = *reinterpret_cast<const f16x8*>(
          fwT + (size_t)(nt * 16 + m) * 160 + ks * 32 + g * 8);
  const int row = base + m;
  f16x8 a[5];
  a[0] = *reinterpret_cast<const f16x8*>(xh0 + (size_t)row * 32 + g * 8);
  a[1] = *reinterpret_cast<const f16x8*>(xh1 + (size_t)row * 64 + g * 8);
  a[2] = *reinterpret_cast<const f16x8*>(xh1 + (size_t)row * 64 + 32 + g * 8);
  a[3] = *reinterpret_cast<const f16x8*>(xh2 + (size_t)row * 64 + g * 8);
  a[4] = *reinterpret_cast<const f16x8*>(xh2 + (size_t)row * 64 + 32 + g * 8);
  f32x4 acc[4];
#pragma unroll
  for (int nt = 0; nt < 4; ++nt) {
    const float fv = fb[nt * 16 + m];
    acc[nt] = (f32x4){fv, fv, fv, fv};
  }
#pragma unroll
  for (int ks = 0; ks < 5; ++ks)
#pragma unroll
    for (int nt = 0; nt < 4; ++nt)
      acc[nt] = __builtin_amdgcn_mfma_f32_16x16x32_f16(a[ks], bf[ks][nt], acc[nt], 0, 0, 0);
#pragma unroll
  for (int r = 0; r < 4; ++r) {
    float* op = out + (size_t)(base + g * 4 + r) * 64 + m;
#pragma unroll
    for (int nt = 0; nt < 4; ++nt) op[nt * 16] = acc[nt][r];
  }
}

extern "C" void kernel_launch(void* const* d_in, const int* in_sizes, int n_in,
                              void* d_out, int out_size, void* d_ws, size_t ws_size,
                              hipStream_t stream) {
  const float* x0 = (const float*)d_in[0];
  const void* eidx = d_in[1];
  const float* attr = (const float*)d_in[2];
  const float* w0 = (const float*)d_in[3];
  const float* root0 = (const float*)d_in[4];
  const float* b0 = (const float*)d_in[5];
  const float* w1 = (const float*)d_in[6];
  const float* root1 = (const float*)d_in[7];
  const float* b1 = (const float*)d_in[8];
  const float* fw = (const float*)d_in[9];
  const float* fb = (const float*)d_in[10];
  float* out = (float*)d_out;
  (void)in_sizes; (void)n_in; (void)out_size;

  char* wsb = (char*)d_ws;
  size_t off = 0;
  auto alloc = [&](size_t bytes) -> void* {
    void* p = wsb + off;
    off += (bytes + 255) & ~(size_t)255;
    return p;
  };
  int* flag = (int*)alloc(256);
  int* src = (int*)alloc(sizeof(int) * EE);
  int* dst = (int*)alloc(sizeof(int) * EE);
  int* srcS = (int*)alloc(sizeof(int) * ELIST_LEN);
  int* posS = (int*)alloc(sizeof(int) * ELIST_LEN);
  f16x4* basS = (f16x4*)alloc(sizeof(f16x4) * ELIST_LEN);
  int* chunkcell = (int*)alloc(sizeof(int) * NBLK_EDGE);
  int* degfill = (int*)alloc(sizeof(int) * 2 * NN);   // degi | fill2, one memset
  int* degi = degfill;
  int* fill2 = degfill + NN;
  int* dstbase = (int*)alloc(sizeof(int) * NN);
  int* bhT = (int*)alloc(sizeof(int) * EB * 16);
  int* blkbaseT = (int*)alloc(sizeof(int) * EB * 16);
  _Float16* xh0 = (_Float16*)alloc(sizeof(_Float16) * NN * 32);
  _Float16* xh1 = (_Float16*)alloc(sizeof(_Float16) * NN * 64);
  _Float16* xh2 = (_Float16*)alloc(sizeof(_Float16) * NN * 64);
  _Float16* wc0 = (_Float16*)alloc(sizeof(_Float16) * 16 * 128 * 64);  // 256KB
  _Float16* wc1 = (_Float16*)alloc(sizeof(_Float16) * 16 * 256 * 64);  // 512KB
  _Float16* fwT = (_Float16*)alloc(sizeof(_Float16) * 64 * 160);
  const size_t common = off;
  const bool twopass = ws_size >= common + sizeof(_Float16) * (size_t)EE * 64;
  _Float16* msg = nullptr;
  float* agg = nullptr;
  if (twopass) msg = (_Float16*)alloc(sizeof(_Float16) * (size_t)EE * 64);
  else         agg = (float*)alloc(sizeof(float) * (size_t)NN * 64);

  hipMemsetAsync(degfill, 0, sizeof(int) * 2 * NN, stream);

  detect_i64<<<1, 64, 0, stream>>>((const long long*)eidx, flag);
  prep_edges<<<EB, 256, 0, stream>>>(eidx, attr, flag, src, dst, degi, bhT);
  scan_fused<<<2, 1024, 0, stream>>>(bhT, blkbaseT, chunkcell, srcS, degi, dstbase);
  scatter_edges<<<EB, 256, 0, stream>>>(attr, blkbaseT, src, dst, dstbase,
                                        fill2, srcS, posS, basS);
  convert_all<<<CONV_BLK, 256, 0, stream>>>(x0, w0, w1, fw, xh0, wc0, wc1, fwT);

  if (twopass) {
    edge_mfma<32, true><<<NBLK_EDGE, 256, 0, stream>>>(xh0, wc0, chunkcell,
                                                       srcS, posS, basS, msg, nullptr);
    pass2_kernel<32><<<NN / 4, 256, 0, stream>>>(msg, dstbase, degi, xh0, root0, b0, xh1);
    edge_mfma<64, true><<<NBLK_EDGE, 256, 0, stream>>>(xh1, wc1, chunkcell,
                                                       srcS, posS, basS, msg, nullptr);
    pass2_kernel<64><<<NN / 4, 256, 0, stream>>>(msg, dstbase, degi, xh1, root1, b1, xh2);
  } else {
    hipMemsetAsync(agg, 0, sizeof(float) * NN * 64, stream);
    edge_mfma<32, false><<<NBLK_EDGE, 256, 0, stream>>>(xh0, wc0, chunkcell,
                                                        srcS, posS, basS, nullptr, agg);
    finalize_kernel<32><<<(NN + 3) / 4, 256, 0, stream>>>(xh0, agg, degi, root0, b0, xh1);
    hipMemsetAsync(agg, 0, sizeof(float) * NN * 64, stream);
    edge_mfma<64, false><<<NBLK_EDGE, 256, 0, stream>>>(xh1, wc1, chunkcell,
                                                        srcS, posS, basS, nullptr, agg);
    finalize_kernel<64><<<(NN + 3) / 4, 256, 0, stream>>>(xh1, agg, degi, root1, b1, xh2);
  }

  out_mfma<<<(NN + 63) / 64, 256, 0, stream>>>(xh0, xh1, xh2, fwT, fb, out);
}

// Round 12
// 258.305 us; speedup vs baseline: 1.1178x; 1.1178x over previous
//
#include <hip/hip_runtime.h>
#include <hip/hip_bf16.h>
#include <hip/hip_fp16.h>

// SplineCNN forward, MI355X round 12.
// R11 -> R12: pass2 regression post-mortem showed the cost was structural:
// 16KB root-LDS staging + sync + 128-LDS-read GEMV per 4-node block. The
// root term is a GEMM -> hoisted into root_mfma<IN> (rt = xh@root + bias,
// f16, msg-permuted layout, ~5us). pass2 is now a pure segment-reduce:
// no LDS, no sync, no template, ~20 VGPR -> max occupancy.

typedef __attribute__((ext_vector_type(8))) _Float16 f16x8;
typedef __attribute__((ext_vector_type(4))) _Float16 f16x4;
typedef __attribute__((ext_vector_type(4))) float f32x4;

constexpr int NN = 50000;       // nodes
constexpr int EE = 800000;      // edges
constexpr int CHUNK = 256;      // edges per block in edge_mfma
constexpr int EB = EE / 256;    // 3125 prep/scatter blocks
static_assert(EE % 256 == 0, "prep grid assumes exact divisibility");
constexpr int ELIST_LEN = EE + 16 * CHUNK;
constexpr int NBLK_EDGE = ELIST_LEN / CHUNK;   // 3141

// ---------------------------------------------------------------- dtype probe
__global__ void detect_i64(const long long* __restrict__ eidx, int* __restrict__ flag) {
  long long v = eidx[threadIdx.x];
  bool ok = (v >= 0) && (v < (long long)NN);
  unsigned long long m = __ballot(ok);
  if (threadIdx.x == 0) flag[0] = (m == ~0ull) ? 1 : 0;
}

// ------------------------------------------------------------------- prep
__global__ __launch_bounds__(256) void prep_edges(
    const void* __restrict__ eidx, const float* __restrict__ attr,
    const int* __restrict__ flag,
    int* __restrict__ src, int* __restrict__ dst,
    int* __restrict__ degi, int* __restrict__ bhT) {
  __shared__ int wc[4][16];
  const int tid = threadIdx.x;
  const int e = blockIdx.x * 256 + tid;
  int s, d;
  if (flag[0]) {
    s = (int)((const long long*)eidx)[e];
    d = (int)((const long long*)eidx)[EE + e];
  } else {
    s = ((const int*)eidx)[e];
    d = ((const int*)eidx)[EE + e];
  }
  src[e] = s;
  dst[e] = d;
  atomicAdd(&degi[d], 1);
  const float v0 = attr[2 * e] * 4.0f, v1 = attr[2 * e + 1] * 4.0f;
  const int bx = min(max((int)floorf(v0), 0), 3);
  const int by = min(max((int)floorf(v1), 0), 3);
  const int c = bx + 4 * by;
  const int wave = tid >> 6, lane = tid & 63;
#pragma unroll
  for (int k = 0; k < 16; ++k) {
    unsigned long long mm = __ballot(c == k);
    if (lane == k) wc[wave][k] = __popcll(mm);
  }
  __syncthreads();
  if (tid < 16)
    bhT[tid * EB + blockIdx.x] = wc[0][tid] + wc[1][tid] + wc[2][tid] + wc[3][tid];
}

// --------------------------------------------------------------- fused scans
__global__ __launch_bounds__(1024) void scan_fused(
    const int* __restrict__ bhT, int* __restrict__ blkbaseT,
    int* __restrict__ chunkcell, int* __restrict__ srcS,
    const int* __restrict__ degi, int* __restrict__ dstbase) {
  const int wave = threadIdx.x >> 6, lane = threadIdx.x & 63;
  if (blockIdx.x == 0) {
    constexpr int CH = (EB + 63) / 64;   // 49
    __shared__ int ofs_s[16];
    __shared__ int tot_s[16];
    int v[CH];
#pragma unroll
    for (int ch = 0; ch < CH; ++ch) {
      const int b = ch * 64 + lane;
      v[ch] = (b < EB) ? bhT[wave * EB + b] : 0;
    }
    {
      int sum = 0;
#pragma unroll
      for (int ch = 0; ch < CH; ++ch) sum += v[ch];
#pragma unroll
      for (int off = 32; off > 0; off >>= 1) sum += __shfl_down(sum, off);
      if (lane == 0) tot_s[wave] = sum;
    }
    __syncthreads();
    if (threadIdx.x == 0) {
      int t = 0;
      for (int c = 0; c < 16; ++c) {
        ofs_s[c] = t;
        t += ((tot_s[c] + CHUNK - 1) / CHUNK) * CHUNK;
      }
    }
    __syncthreads();
    {  // chunk -> cell map; padding chunks get -1
      const int nch = (tot_s[wave] + CHUNK - 1) / CHUNK;
      const int cb = ofs_s[wave] / CHUNK;
      for (int i = lane; i < nch; i += 64) chunkcell[cb + i] = wave;
      if (wave == 15) {
        const int totch = cb + nch;
        for (int i = totch + lane; i < NBLK_EDGE; i += 64) chunkcell[i] = -1;
      }
    }
    {  // srcS pad sentinels for this cell's segment
      const int startp = ofs_s[wave] + tot_s[wave];
      const int endp = ofs_s[wave] + ((tot_s[wave] + CHUNK - 1) / CHUNK) * CHUNK;
      for (int p = startp + lane; p < endp; p += 64) srcS[p] = -1;
    }
    int running = ofs_s[wave];
#pragma unroll
    for (int ch = 0; ch < CH; ++ch) {
      int inc = v[ch];
#pragma unroll
      for (int off = 1; off < 64; off <<= 1) {
        int n = __shfl_up(inc, off);
        if (lane >= off) inc += n;
      }
      const int b = ch * 64 + lane;
      if (b < EB) blkbaseT[wave * EB + b] = running + inc - v[ch];
      running += __shfl(inc, 63);
    }
  } else {
    constexpr int SEG = NN / 16;          // 3125
    constexpr int CH = (SEG + 63) / 64;   // 49
    __shared__ int wofs[16];
    const int nbase = wave * SEG;
    int v[CH];
#pragma unroll
    for (int ch = 0; ch < CH; ++ch) {
      const int i = ch * 64 + lane;
      v[ch] = (i < SEG) ? degi[nbase + i] : 0;
    }
    {
      int sum = 0;
#pragma unroll
      for (int ch = 0; ch < CH; ++ch) sum += v[ch];
#pragma unroll
      for (int off = 32; off > 0; off >>= 1) sum += __shfl_down(sum, off);
      if (lane == 0) wofs[wave] = sum;
    }
    __syncthreads();
    if (threadIdx.x == 0) {
      int t = 0;
      for (int w2 = 0; w2 < 16; ++w2) { int tv = wofs[w2]; wofs[w2] = t; t += tv; }
    }
    __syncthreads();
    int running = wofs[wave];
#pragma unroll
    for (int ch = 0; ch < CH; ++ch) {
      int inc = v[ch];
#pragma unroll
      for (int off = 1; off < 64; off <<= 1) {
        int n = __shfl_up(inc, off);
        if (lane >= off) inc += n;
      }
      const int i = ch * 64 + lane;
      if (i < SEG) dstbase[nbase + i] = running + inc - v[ch];
      running += __shfl(inc, 63);
    }
  }
}

// Deterministic cell-sorted scatter; recomputes cell+basis from attr.
__global__ __launch_bounds__(256) void scatter_edges(
    const float* __restrict__ attr, const int* __restrict__ blkbaseT,
    const int* __restrict__ srcArr, const int* __restrict__ dstArr,
    const int* __restrict__ dstbase, int* __restrict__ fill2,
    int* __restrict__ srcS, int* __restrict__ posS, f16x4* __restrict__ basS) {
  __shared__ int wc[4][16];
  __shared__ int bs[4][16];
  const int tid = threadIdx.x;
  const int e = blockIdx.x * 256 + tid;
  const float v0 = attr[2 * e] * 4.0f, v1 = attr[2 * e + 1] * 4.0f;
  const float fl0 = floorf(v0), fl1 = floorf(v1);
  const float fr0 = v0 - fl0, fr1 = v1 - fl1;
  const int bx = min(max((int)fl0, 0), 3);
  const int by = min(max((int)fl1, 0), 3);
  const int c = bx + 4 * by;
  const f16x4 bq = {(_Float16)((1.0f - fr0) * (1.0f - fr1)),
                    (_Float16)(fr0 * (1.0f - fr1)),
                    (_Float16)((1.0f - fr0) * fr1),
                    (_Float16)(fr0 * fr1)};
  const int wave = tid >> 6, lane = tid & 63;
  int rank = 0;
#pragma unroll
  for (int k = 0; k < 16; ++k) {
    unsigned long long mm = __ballot(c == k);
    if (k == c) rank = __popcll(mm & ((1ull << lane) - 1ull));
    if (lane == k) wc[wave][k] = __popcll(mm);
  }
  const int d = dstArr[e];
  const int mypos = dstbase[d] + atomicAdd(&fill2[d], 1);
  __syncthreads();
  if (tid < 16) {
    int running = blkbaseT[tid * EB + blockIdx.x];
#pragma unroll
    for (int w = 0; w < 4; ++w) { bs[w][tid] = running; running += wc[w][tid]; }
  }
  __syncthreads();
  const int p = bs[wave][c] + rank;
  srcS[p] = srcArr[e];
  posS[p] = mypos;
  basS[p] = bq;
}

// ------------------------------------------------- fused one-shot converts
constexpr int F2H_LEN8 = NN * 32 / 8;                 // 200000
constexpr int F2H_BLK = (F2H_LEN8 + 255) / 256;       // 782
constexpr int CW32_BLK = 4 * 16;                      // 64
constexpr int CW64_BLK = 8 * 16;                      // 128
constexpr int CFW_BLK = (64 * 160) / 256;             // 40
constexpr int CRT0_BLK = (64 * 32) / 256;             // 8
constexpr int CRT1_BLK = (64 * 64) / 256;             // 16
constexpr int CONV_BLK = F2H_BLK + CW32_BLK + CW64_BLK + CFW_BLK + CRT0_BLK + CRT1_BLK;

template <int IN>
__device__ __forceinline__ void conv_w_body(
    const float* __restrict__ w, _Float16* __restrict__ wcell, int c, int o) {
  constexpr int K = 4 * IN;
  constexpr int RS = K * 2;
  constexpr int OPR = K / 8;
  const int bx = c & 3, by = c >> 2;
  const int n = o / OPR;
  const int k0 = (o - n * OPR) * 8;
  const int ks = k0 >> 5;
  const int g2 = (k0 & 31) >> 3;
  const int s = (IN == 64) ? (ks & 3) : ks;
  const int i0 = ((IN == 64) ? (ks >> 2) * 32 : 0) + g2 * 8;
  const int kk = (bx + (s & 1)) + 5 * (by + (s >> 1));
  const float* wp = w + ((size_t)kk * IN + i0) * 64 + n;
  f16x8 v;
#pragma unroll
  for (int j = 0; j < 8; ++j) v[j] = (_Float16)wp[(size_t)j * 64];
  const int byte = n * RS + ((k0 * 2) ^ ((n & 15) << 4));
  *reinterpret_cast<f16x8*>(
      reinterpret_cast<char*>(wcell) + (size_t)c * (RS * 64) + byte) = v;
}

__global__ __launch_bounds__(256) void convert_all(
    const float* __restrict__ x0, const float* __restrict__ w0,
    const float* __restrict__ w1, const float* __restrict__ fw,
    const float* __restrict__ root0, const float* __restrict__ root1,
    _Float16* __restrict__ xh0, _Float16* __restrict__ wc0,
    _Float16* __restrict__ wc1, _Float16* __restrict__ fwT,
    _Float16* __restrict__ rt0T, _Float16* __restrict__ rt1T) {
  const int b = blockIdx.x, tid = threadIdx.x;
  if (b < F2H_BLK) {
    const int i = b * 256 + tid;
    if (i >= F2H_LEN8) return;
    const float4 a = reinterpret_cast<const float4*>(x0)[i * 2];
    const float4 bb = reinterpret_cast<const float4*>(x0)[i * 2 + 1];
    f16x8 v = {(_Float16)a.x, (_Float16)a.y, (_Float16)a.z, (_Float16)a.w,
               (_Float16)bb.x, (_Float16)bb.y, (_Float16)bb.z, (_Float16)bb.w};
    reinterpret_cast<f16x8*>(xh0)[i] = v;
  } else if (b < F2H_BLK + CW32_BLK) {
    const int r = b - F2H_BLK;
    conv_w_body<32>(w0, wc0, r >> 2, (r & 3) * 256 + tid);
  } else if (b < F2H_BLK + CW32_BLK + CW64_BLK) {
    const int r = b - F2H_BLK - CW32_BLK;
    conv_w_body<64>(w1, wc1, r >> 3, (r & 7) * 256 + tid);
  } else if (b < F2H_BLK + CW32_BLK + CW64_BLK + CFW_BLK) {
    const int i = (b - F2H_BLK - CW32_BLK - CW64_BLK) * 256 + tid;  // < 10240
    const int n = i / 160, k = i - n * 160;
    fwT[i] = (_Float16)fw[k * 64 + n];
  } else if (b < F2H_BLK + CW32_BLK + CW64_BLK + CFW_BLK + CRT0_BLK) {
    const int i = (b - F2H_BLK - CW32_BLK - CW64_BLK - CFW_BLK) * 256 + tid;  // < 2048
    const int n = i / 32, k = i - n * 32;
    rt0T[i] = (_Float16)root0[k * 64 + n];
  } else {
    const int i = (b - F2H_BLK - CW32_BLK - CW64_BLK - CFW_BLK - CRT0_BLK) * 256 + tid;
    const int n = i / 64, k = i - n * 64;   // i < 4096
    rt1T[i] = (_Float16)root1[k * 64 + n];
  }
}

// --------------------------------------------------------------- root GEMM
// rt[n] = xh_in[n] @ root + bias, f16 output in the msg-permuted channel
// layout (channel nt*16+m at position m*4+nt) so pass2/edge read it cheaply.
template <int IN>
__global__ __launch_bounds__(256) void root_mfma(
    const _Float16* __restrict__ xh, const _Float16* __restrict__ rootT,
    const float* __restrict__ bias, _Float16* __restrict__ rth) {
  constexpr int KS = IN / 32;
  const int lane = threadIdx.x & 63, wave = threadIdx.x >> 6;
  const int g = lane >> 4, m = lane & 15;
  const int base = blockIdx.x * 64 + wave * 16;
  if (base >= NN) return;
  f16x8 bf[KS][4];
#pragma unroll
  for (int ks = 0; ks < KS; ++ks)
#pragma unroll
    for (int nt = 0; nt < 4; ++nt)
      bf[ks][nt] = *reinterpret_cast<const f16x8*>(
          rootT + (size_t)(nt * 16 + m) * IN + ks * 32 + g * 8);
  const int row = base + m;
  f16x8 a[KS];
#pragma unroll
  for (int ks = 0; ks < KS; ++ks)
    a[ks] = *reinterpret_cast<const f16x8*>(xh + (size_t)row * IN + ks * 32 + g * 8);
  f32x4 acc[4];
#pragma unroll
  for (int nt = 0; nt < 4; ++nt) {
    const float fv = bias[nt * 16 + m];
    acc[nt] = (f32x4){fv, fv, fv, fv};
  }
#pragma unroll
  for (int ks = 0; ks < KS; ++ks)
#pragma unroll
    for (int nt = 0; nt < 4; ++nt)
      acc[nt] = __builtin_amdgcn_mfma_f32_16x16x32_f16(a[ks], bf[ks][nt], acc[nt], 0, 0, 0);
#pragma unroll
  for (int r = 0; r < 4; ++r) {
    const int node = base + g * 4 + r;
    f16x4 pv = {(_Float16)acc[0][r], (_Float16)acc[1][r],
                (_Float16)acc[2][r], (_Float16)acc[3][r]};
    *reinterpret_cast<f16x4*>(rth + (size_t)node * 64 + m * 4) = pv;
  }
}

// ------------------------------------------------------------------- edge msg
template <int IN, bool TWOPASS>
__global__ __launch_bounds__(256) void edge_mfma(
    const _Float16* __restrict__ xh, const _Float16* __restrict__ wcell,
    const int* __restrict__ chunkcell,
    const int* __restrict__ srcS, const int* __restrict__ posS,
    const f16x4* __restrict__ basS,
    _Float16* __restrict__ msg, float* __restrict__ agg) {
  constexpr int K = 4 * IN;
  constexpr int KSTEPS = K / 32;
  constexpr int RS = K * 2;            // LDS row stride bytes
  constexpr int OPR = K / 8;           // 16B chunks per row
  constexpr int TILES = CHUNK / 64;    // 4
  constexpr int NCH = (IN == 64) ? 2 : 1;
  __shared__ f16x8 Wt[64 * OPR];
  const int tid = threadIdx.x;
  const int c = chunkcell[blockIdx.x];
  if (c < 0) return;                   // fully-padded chunk
  const int base = blockIdx.x * CHUNK;
  const int lane = tid & 63;
  const int wave = tid >> 6;
  const int g = lane >> 4, m = lane & 15;
  const int wbase = base + wave * (CHUNK / 4);
  int sv_t[TILES], po_t[TILES];
  f16x4 bas_t[TILES];
#pragma unroll
  for (int t = 0; t < TILES; ++t) sv_t[t] = srcS[wbase + t * 16 + m];
#pragma unroll
  for (int t = 0; t < TILES; ++t) po_t[t] = posS[wbase + t * 16 + m];
#pragma unroll
  for (int t = 0; t < TILES; ++t) bas_t[t] = basS[wbase + t * 16 + m];
  {
    const f16x8* gw = reinterpret_cast<const f16x8*>(wcell) + (size_t)c * (64 * OPR);
    for (int o = tid; o < 64 * OPR; o += 256) Wt[o] = gw[o];
  }
  __syncthreads();
  f16x8 xc[TILES][NCH];
#pragma unroll
  for (int t = 0; t < TILES; ++t) {
    const int row = (sv_t[t] >= 0) ? sv_t[t] : 0;
    const f16x8* xr = reinterpret_cast<const f16x8*>(xh + (size_t)row * IN);
    xc[t][0] = xr[g];
    if constexpr (IN == 64) xc[t][1] = xr[4 + g];
  }
#pragma unroll
  for (int t = 0; t < TILES; ++t) {
    f32x4 acc[4];
#pragma unroll
    for (int nt = 0; nt < 4; ++nt) acc[nt] = (f32x4){0.f, 0.f, 0.f, 0.f};
#pragma unroll
    for (int ks = 0; ks < KSTEPS; ++ks) {
      const int s = (IN == 64) ? (ks & 3) : ks;
      const f16x8 xin = (IN == 64 && (ks >> 2)) ? xc[t][1] : xc[t][0];
      const f16x8 a = xin * bas_t[t][s];
#pragma unroll
      for (int nt = 0; nt < 4; ++nt) {
        const int n = nt * 16 + m;
        const int byte = n * RS + (((ks * 64) + g * 16) ^ ((n & 15) << 4));
        acc[nt] = __builtin_amdgcn_mfma_f32_16x16x32_f16(a, Wt[byte >> 4], acc[nt], 0, 0, 0);
      }
    }
#pragma unroll
    for (int r = 0; r < 4; ++r) {
      const int m2 = g * 4 + r;
      const int er = __shfl(sv_t[t], m2);
      const int pr = __shfl(po_t[t], m2);
      if (er >= 0) {
        if constexpr (TWOPASS) {
          f16x4 pv = {(_Float16)acc[0][r], (_Float16)acc[1][r],
                      (_Float16)acc[2][r], (_Float16)acc[3][r]};
          __builtin_nontemporal_store(
              pv, reinterpret_cast<f16x4*>(msg + (size_t)pr * 64 + m * 4));
        } else {
          float* ap = agg + (size_t)pr * 64 + m;
#pragma unroll
          for (int nt = 0; nt < 4; ++nt) atomicAdd(ap + nt * 16, acc[nt][r]);
        }
      }
    }
  }
}

// --------------------------------------------------------------- pass2
// Pure segment-reduce: xh_out = relu(mean(msg segment) + rt). No LDS, no
// sync, no GEMV. Lane group q reads rows j+q (f16x4 8B), 16 rows in flight;
// shfl_xor(16,32) combines; rt (precomputed root-term) in permuted layout.
__global__ __launch_bounds__(256) void pass2_kernel(
    const _Float16* __restrict__ msg, const int* __restrict__ dstbase,
    const int* __restrict__ degi, const _Float16* __restrict__ rth,
    _Float16* __restrict__ xh_out) {
  const int wave = threadIdx.x >> 6, lane = threadIdx.x & 63;
  const int n = blockIdx.x * 4 + wave;   // grid sized so n < NN always
  const int q = lane >> 4, m = lane & 15;
  const _Float16 rv = rth[(size_t)n * 64 + m * 4 + q];  // channel q*16+m
  const int b0 = dstbase[n], dg = degi[n];
  const _Float16* mp = msg + (size_t)b0 * 64 + m * 4;
  float a0 = 0.f, a1 = 0.f, a2 = 0.f, a3 = 0.f;
  const int nfull = dg & ~15;
  int j0 = 0;
  for (; j0 < nfull; j0 += 16) {
    const _Float16* bp = mp + (size_t)j0 * 64;
#pragma unroll
    for (int u = 0; u < 4; ++u) {
      const f16x4 v = *reinterpret_cast<const f16x4*>(bp + (size_t)(u * 4 + q) * 64);
      a0 += (float)v[0]; a1 += (float)v[1]; a2 += (float)v[2]; a3 += (float)v[3];
    }
  }
  if (j0 < dg) {  // masked tail (<16 rows)
#pragma unroll
    for (int u = 0; u < 4; ++u) {
      const int jj = j0 + u * 4 + q;
      const int jc = min(jj, dg - 1);
      const f16x4 v = *reinterpret_cast<const f16x4*>(mp + (size_t)jc * 64);
      const float wv = (jj < dg) ? 1.0f : 0.0f;
      a0 = fmaf(wv, (float)v[0], a0);
      a1 = fmaf(wv, (float)v[1], a1);
      a2 = fmaf(wv, (float)v[2], a2);
      a3 = fmaf(wv, (float)v[3], a3);
    }
  }
  a0 += __shfl_xor(a0, 16); a0 += __shfl_xor(a0, 32);
  a1 += __shfl_xor(a1, 16); a1 += __shfl_xor(a1, 32);
  a2 += __shfl_xor(a2, 16); a2 += __shfl_xor(a2, 32);
  a3 += __shfl_xor(a3, 16); a3 += __shfl_xor(a3, 32);
  const float acc = (q == 0) ? a0 : (q == 1) ? a1 : (q == 2) ? a2 : a3;
  const float r = fmaxf(acc / fmaxf((float)dg, 1.0f) + (float)rv, 0.0f);
  xh_out[(size_t)n * 64 + lane] = (_Float16)r;   // lane == channel q*16+m
}

// --------------------------------------------------------------- finalize
// (atomic-fallback path only)
template <int IN>
__global__ __launch_bounds__(256) void finalize_kernel(
    const _Float16* __restrict__ xh_in, const float* __restrict__ agg,
    const int* __restrict__ degi, const float* __restrict__ root,
    const float* __restrict__ bias, _Float16* __restrict__ xh_out) {
  __shared__ float rl[IN * 64];
  for (int idx = threadIdx.x; idx < IN * 16; idx += 256)
    reinterpret_cast<float4*>(rl)[idx] = reinterpret_cast<const float4*>(root)[idx];
  __syncthreads();
  const int wave = threadIdx.x >> 6, lane = threadIdx.x & 63;
  const int n = blockIdx.x * 4 + wave;
  if (n >= NN) return;
  const float d = fmaxf((float)degi[n], 1.0f);
  float r = agg[(size_t)n * 64 + lane] / d + bias[lane];
  const _Float16* xr = xh_in + (size_t)n * IN;
#pragma unroll 8
  for (int i = 0; i < IN; ++i) r = fmaf((float)xr[i], rl[i * 64 + lane], r);
  r = fmaxf(r, 0.0f);
  xh_out[(size_t)n * 64 + lane] = (_Float16)r;
}

// ------------------------------------------------------------------- output
__global__ __launch_bounds__(256) void out_mfma(
    const _Float16* __restrict__ xh0, const _Float16* __restrict__ xh1,
    const _Float16* __restrict__ xh2, const _Float16* __restrict__ fwT,
    const float* __restrict__ fb, float* __restrict__ out) {
  const int lane = threadIdx.x & 63, wave = threadIdx.x >> 6;
  const int g = lane >> 4, m = lane & 15;
  const int base = blockIdx.x * 64 + wave * 16;   // NN % 16 == 0
  if (base >= NN) return;
  f16x8 bf[5][4];
#pragma unroll
  for (int ks = 0; ks < 5; ++ks)
#pragma unroll
    for (int nt = 0; nt < 4; ++nt)
      bf[ks][nt] = *reinterpret_cast<const f16x8*>(
          fwT + (size_t)(nt * 16 + m) * 160 + ks * 32 + g * 8);
  const int row = base + m;
  f16x8 a[5];
  a[0] = *reinterpret_cast<const f16x8*>(xh0 + (size_t)row * 32 + g * 8);
  a[1] = *reinterpret_cast<const f16x8*>(xh1 + (size_t)row * 64 + g * 8);
  a[2] = *reinterpret_cast<const f16x8*>(xh1 + (size_t)row * 64 + 32 + g * 8);
  a[3] = *reinterpret_cast<const f16x8*>(xh2 + (size_t)row * 64 + g * 8);
  a[4] = *reinterpret_cast<const f16x8*>(xh2 + (size_t)row * 64 + 32 + g * 8);
  f32x4 acc[4];
#pragma unroll
  for (int nt = 0; nt < 4; ++nt) {
    const float fv = fb[nt * 16 + m];
    acc[nt] = (f32x4){fv, fv, fv, fv};
  }
#pragma unroll
  for (int ks = 0; ks < 5; ++ks)
#pragma unroll
    for (int nt = 0; nt < 4; ++nt)
      acc[nt] = __builtin_amdgcn_mfma_f32_16x16x32_f16(a[ks], bf[ks][nt], acc[nt], 0, 0, 0);
#pragma unroll
  for (int r = 0; r < 4; ++r) {
    float* op = out + (size_t)(base + g * 4 + r) * 64 + m;
#pragma unroll
    for (int nt = 0; nt < 4; ++nt) op[nt * 16] = acc[nt][r];
  }
}

extern "C" void kernel_launch(void* const* d_in, const int* in_sizes, int n_in,
                              void* d_out, int out_size, void* d_ws, size_t ws_size,
                              hipStream_t stream) {
  const float* x0 = (const float*)d_in[0];
  const void* eidx = d_in[1];
  const float* attr = (const float*)d_in[2];
  const float* w0 = (const float*)d_in[3];
  const float* root0 = (const float*)d_in[4];
  const float* b0 = (const float*)d_in[5];
  const float* w1 = (const float*)d_in[6];
  const float* root1 = (const float*)d_in[7];
  const float* b1 = (const float*)d_in[8];
  const float* fw = (const float*)d_in[9];
  const float* fb = (const float*)d_in[10];
  float* out = (float*)d_out;
  (void)in_sizes; (void)n_in; (void)out_size;

  char* wsb = (char*)d_ws;
  size_t off = 0;
  auto alloc = [&](size_t bytes) -> void* {
    void* p = wsb + off;
    off += (bytes + 255) & ~(size_t)255;
    return p;
  };
  int* flag = (int*)alloc(256);
  int* src = (int*)alloc(sizeof(int) * EE);
  int* dst = (int*)alloc(sizeof(int) * EE);
  int* srcS = (int*)alloc(sizeof(int) * ELIST_LEN);
  int* posS = (int*)alloc(sizeof(int) * ELIST_LEN);
  f16x4* basS = (f16x4*)alloc(sizeof(f16x4) * ELIST_LEN);
  int* chunkcell = (int*)alloc(sizeof(int) * NBLK_EDGE);
  int* degfill = (int*)alloc(sizeof(int) * 2 * NN);   // degi | fill2, one memset
  int* degi = degfill;
  int* fill2 = degfill + NN;
  int* dstbase = (int*)alloc(sizeof(int) * NN);
  int* bhT = (int*)alloc(sizeof(int) * EB * 16);
  int* blkbaseT = (int*)alloc(sizeof(int) * EB * 16);
  _Float16* xh0 = (_Float16*)alloc(sizeof(_Float16) * NN * 32);
  _Float16* xh1 = (_Float16*)alloc(sizeof(_Float16) * NN * 64);
  _Float16* xh2 = (_Float16*)alloc(sizeof(_Float16) * NN * 64);
  _Float16* rth = (_Float16*)alloc(sizeof(_Float16) * NN * 64);
  _Float16* wc0 = (_Float16*)alloc(sizeof(_Float16) * 16 * 128 * 64);  // 256KB
  _Float16* wc1 = (_Float16*)alloc(sizeof(_Float16) * 16 * 256 * 64);  // 512KB
  _Float16* fwT = (_Float16*)alloc(sizeof(_Float16) * 64 * 160);
  _Float16* rt0T = (_Float16*)alloc(sizeof(_Float16) * 64 * 32);
  _Float16* rt1T = (_Float16*)alloc(sizeof(_Float16) * 64 * 64);
  const size_t common = off;
  const bool twopass = ws_size >= common + sizeof(_Float16) * (size_t)EE * 64;
  _Float16* msg = nullptr;
  float* agg = nullptr;
  if (twopass) msg = (_Float16*)alloc(sizeof(_Float16) * (size_t)EE * 64);
  else         agg = (float*)alloc(sizeof(float) * (size_t)NN * 64);

  hipMemsetAsync(degfill, 0, sizeof(int) * 2 * NN, stream);

  detect_i64<<<1, 64, 0, stream>>>((const long long*)eidx, flag);
  prep_edges<<<EB, 256, 0, stream>>>(eidx, attr, flag, src, dst, degi, bhT);
  scan_fused<<<2, 1024, 0, stream>>>(bhT, blkbaseT, chunkcell, srcS, degi, dstbase);
  scatter_edges<<<EB, 256, 0, stream>>>(attr, blkbaseT, src, dst, dstbase,
                                        fill2, srcS, posS, basS);
  convert_all<<<CONV_BLK, 256, 0, stream>>>(x0, w0, w1, fw, root0, root1,
                                            xh0, wc0, wc1, fwT, rt0T, rt1T);

  if (twopass) {
    root_mfma<32><<<(NN + 63) / 64, 256, 0, stream>>>(xh0, rt0T, b0, rth);
    edge_mfma<32, true><<<NBLK_EDGE, 256, 0, stream>>>(xh0, wc0, chunkcell,
                                                       srcS, posS, basS, msg, nullptr);
    pass2_kernel<<<NN / 4, 256, 0, stream>>>(msg, dstbase, degi, rth, xh1);
    root_mfma<64><<<(NN + 63) / 64, 256, 0, stream>>>(xh1, rt1T, b1, rth);
    edge_mfma<64, true><<<NBLK_EDGE, 256, 0, stream>>>(xh1, wc1, chunkcell,
                                                       srcS, posS, basS, msg, nullptr);
    pass2_kernel<<<NN / 4, 256, 0, stream>>>(msg, dstbase, degi, rth, xh2);
  } else {
    hipMemsetAsync(agg, 0, sizeof(float) * NN * 64, stream);
    edge_mfma<32, false><<<NBLK_EDGE, 256, 0, stream>>>(xh0, wc0, chunkcell,
                                                        srcS, posS, basS, nullptr, agg);
    finalize_kernel<32><<<(NN + 3) / 4, 256, 0, stream>>>(xh0, agg, degi, root0, b0, xh1);
    hipMemsetAsync(agg, 0, sizeof(float) * NN * 64, stream);
    edge_mfma<64, false><<<NBLK_EDGE, 256, 0, stream>>>(xh1, wc1, chunkcell,
                                                        srcS, posS, basS, nullptr, agg);
    finalize_kernel<64><<<(NN + 3) / 4, 256, 0, stream>>>(xh1, agg, degi, root1, b1, xh2);
  }

  out_mfma<<<(NN + 63) / 64, 256, 0, stream>>>(xh0, xh1, xh2, fwT, fb, out);
}

// Round 13
// 235.475 us; speedup vs baseline: 1.2261x; 1.0970x over previous
//
#include <hip/hip_runtime.h>
#include <hip/hip_bf16.h>
#include <hip/hip_fp16.h>

// SplineCNN forward, MI355X round 13.
// R12 -> R13: no dominant kernel left; attacked msg cache residency and
// launch serialization. (1) msg stores NT -> plain: lines are fully written
// (no write-allocate) and 102MB fits L3, so pass2 reads become LLC hits.
// (2) Merged independent kernels by block-range: {detect+memset},
// {prep+convert}, {edge+root} -> 12 launches down to 9. (3) srcS/posS packed
// as int2 (one 8B metadata load).

typedef __attribute__((ext_vector_type(8))) _Float16 f16x8;
typedef __attribute__((ext_vector_type(4))) _Float16 f16x4;
typedef __attribute__((ext_vector_type(4))) float f32x4;

constexpr int NN = 50000;       // nodes
constexpr int EE = 800000;      // edges
constexpr int CHUNK = 256;      // edges per block in edge_mfma
constexpr int EB = EE / 256;    // 3125 prep/scatter blocks
static_assert(EE % 256 == 0, "prep grid assumes exact divisibility");
constexpr int ELIST_LEN = EE + 16 * CHUNK;
constexpr int NBLK_EDGE = ELIST_LEN / CHUNK;   // 3141
constexpr int RT_BLK = (NN + 63) / 64;         // 782 root-GEMM blocks

// ------------------------------------------------- detect + workspace init
// Block 0 wave 0: int64-vs-int32 probe on edge_index. All blocks: zero the
// degi|fill2 region (2*NN ints).
__global__ __launch_bounds__(256) void detect_init(
    const long long* __restrict__ eidx, int* __restrict__ flag,
    int* __restrict__ degfill) {
  if (blockIdx.x == 0 && threadIdx.x < 64) {
    long long v = eidx[threadIdx.x];
    bool ok = (v >= 0) && (v < (long long)NN);
    unsigned long long m = __ballot(ok);
    if (threadIdx.x == 0) flag[0] = (m == ~0ull) ? 1 : 0;
  }
  const int i = blockIdx.x * 256 + threadIdx.x;
  if (i < 2 * NN) degfill[i] = 0;
}

// ------------------------------------------------- prep + one-shot converts
constexpr int F2H_LEN8 = NN * 32 / 8;                 // 200000
constexpr int F2H_BLK = (F2H_LEN8 + 255) / 256;       // 782
constexpr int CW32_BLK = 4 * 16;                      // 64
constexpr int CW64_BLK = 8 * 16;                      // 128
constexpr int CFW_BLK = (64 * 160) / 256;             // 40
constexpr int CRT0_BLK = (64 * 32) / 256;             // 8
constexpr int CRT1_BLK = (64 * 64) / 256;             // 16
constexpr int CONV_BLK = F2H_BLK + CW32_BLK + CW64_BLK + CFW_BLK + CRT0_BLK + CRT1_BLK;

template <int IN>
__device__ __forceinline__ void conv_w_body(
    const float* __restrict__ w, _Float16* __restrict__ wcell, int c, int o) {
  constexpr int K = 4 * IN;
  constexpr int RS = K * 2;
  constexpr int OPR = K / 8;
  const int bx = c & 3, by = c >> 2;
  const int n = o / OPR;
  const int k0 = (o - n * OPR) * 8;
  const int ks = k0 >> 5;
  const int g2 = (k0 & 31) >> 3;
  const int s = (IN == 64) ? (ks & 3) : ks;
  const int i0 = ((IN == 64) ? (ks >> 2) * 32 : 0) + g2 * 8;
  const int kk = (bx + (s & 1)) + 5 * (by + (s >> 1));
  const float* wp = w + ((size_t)kk * IN + i0) * 64 + n;
  f16x8 v;
#pragma unroll
  for (int j = 0; j < 8; ++j) v[j] = (_Float16)wp[(size_t)j * 64];
  const int byte = n * RS + ((k0 * 2) ^ ((n & 15) << 4));
  *reinterpret_cast<f16x8*>(
      reinterpret_cast<char*>(wcell) + (size_t)c * (RS * 64) + byte) = v;
}

// blocks [0,EB): prep (src/dst/deg/cell-hist); [EB, EB+CONV_BLK): converts.
__global__ __launch_bounds__(256) void prep_conv(
    const void* __restrict__ eidx, const float* __restrict__ attr,
    const int* __restrict__ flag,
    int* __restrict__ src, int* __restrict__ dst,
    int* __restrict__ degi, int* __restrict__ bhT,
    const float* __restrict__ x0, const float* __restrict__ w0,
    const float* __restrict__ w1, const float* __restrict__ fw,
    const float* __restrict__ root0, const float* __restrict__ root1,
    _Float16* __restrict__ xh0, _Float16* __restrict__ wc0,
    _Float16* __restrict__ wc1, _Float16* __restrict__ fwT,
    _Float16* __restrict__ rt0T, _Float16* __restrict__ rt1T) {
  __shared__ int wc[4][16];
  const int tid = threadIdx.x;
  if (blockIdx.x < EB) {
    const int e = blockIdx.x * 256 + tid;
    int s, d;
    if (flag[0]) {
      s = (int)((const long long*)eidx)[e];
      d = (int)((const long long*)eidx)[EE + e];
    } else {
      s = ((const int*)eidx)[e];
      d = ((const int*)eidx)[EE + e];
    }
    src[e] = s;
    dst[e] = d;
    atomicAdd(&degi[d], 1);
    const float v0 = attr[2 * e] * 4.0f, v1 = attr[2 * e + 1] * 4.0f;
    const int bx = min(max((int)floorf(v0), 0), 3);
    const int by = min(max((int)floorf(v1), 0), 3);
    const int c = bx + 4 * by;
    const int wave = tid >> 6, lane = tid & 63;
#pragma unroll
    for (int k = 0; k < 16; ++k) {
      unsigned long long mm = __ballot(c == k);
      if (lane == k) wc[wave][k] = __popcll(mm);
    }
    __syncthreads();
    if (tid < 16)
      bhT[tid * EB + blockIdx.x] = wc[0][tid] + wc[1][tid] + wc[2][tid] + wc[3][tid];
    return;
  }
  const int b = blockIdx.x - EB;
  if (b < F2H_BLK) {
    const int i = b * 256 + tid;
    if (i >= F2H_LEN8) return;
    const float4 a = reinterpret_cast<const float4*>(x0)[i * 2];
    const float4 bb = reinterpret_cast<const float4*>(x0)[i * 2 + 1];
    f16x8 v = {(_Float16)a.x, (_Float16)a.y, (_Float16)a.z, (_Float16)a.w,
               (_Float16)bb.x, (_Float16)bb.y, (_Float16)bb.z, (_Float16)bb.w};
    reinterpret_cast<f16x8*>(xh0)[i] = v;
  } else if (b < F2H_BLK + CW32_BLK) {
    const int r = b - F2H_BLK;
    conv_w_body<32>(w0, wc0, r >> 2, (r & 3) * 256 + tid);
  } else if (b < F2H_BLK + CW32_BLK + CW64_BLK) {
    const int r = b - F2H_BLK - CW32_BLK;
    conv_w_body<64>(w1, wc1, r >> 3, (r & 7) * 256 + tid);
  } else if (b < F2H_BLK + CW32_BLK + CW64_BLK + CFW_BLK) {
    const int i = (b - F2H_BLK - CW32_BLK - CW64_BLK) * 256 + tid;  // < 10240
    const int n = i / 160, k = i - n * 160;
    fwT[i] = (_Float16)fw[k * 64 + n];
  } else if (b < F2H_BLK + CW32_BLK + CW64_BLK + CFW_BLK + CRT0_BLK) {
    const int i = (b - F2H_BLK - CW32_BLK - CW64_BLK - CFW_BLK) * 256 + tid;
    const int n = i / 32, k = i - n * 32;   // i < 2048
    rt0T[i] = (_Float16)root0[k * 64 + n];
  } else {
    const int i = (b - F2H_BLK - CW32_BLK - CW64_BLK - CFW_BLK - CRT0_BLK) * 256 + tid;
    const int n = i / 64, k = i - n * 64;   // i < 4096
    rt1T[i] = (_Float16)root1[k * 64 + n];
  }
}

// --------------------------------------------------------------- fused scans
__global__ __launch_bounds__(1024) void scan_fused(
    const int* __restrict__ bhT, int* __restrict__ blkbaseT,
    int* __restrict__ chunkcell, int2* __restrict__ posrcS,
    const int* __restrict__ degi, int* __restrict__ dstbase) {
  const int wave = threadIdx.x >> 6, lane = threadIdx.x & 63;
  if (blockIdx.x == 0) {
    constexpr int CH = (EB + 63) / 64;   // 49
    __shared__ int ofs_s[16];
    __shared__ int tot_s[16];
    int v[CH];
#pragma unroll
    for (int ch = 0; ch < CH; ++ch) {
      const int b = ch * 64 + lane;
      v[ch] = (b < EB) ? bhT[wave * EB + b] : 0;
    }
    {
      int sum = 0;
#pragma unroll
      for (int ch = 0; ch < CH; ++ch) sum += v[ch];
#pragma unroll
      for (int off = 32; off > 0; off >>= 1) sum += __shfl_down(sum, off);
      if (lane == 0) tot_s[wave] = sum;
    }
    __syncthreads();
    if (threadIdx.x == 0) {
      int t = 0;
      for (int c = 0; c < 16; ++c) {
        ofs_s[c] = t;
        t += ((tot_s[c] + CHUNK - 1) / CHUNK) * CHUNK;
      }
    }
    __syncthreads();
    {  // chunk -> cell map; padding chunks get -1
      const int nch = (tot_s[wave] + CHUNK - 1) / CHUNK;
      const int cb = ofs_s[wave] / CHUNK;
      for (int i = lane; i < nch; i += 64) chunkcell[cb + i] = wave;
      if (wave == 15) {
        const int totch = cb + nch;
        for (int i = totch + lane; i < NBLK_EDGE; i += 64) chunkcell[i] = -1;
      }
    }
    {  // pad sentinels for this cell's segment
      const int startp = ofs_s[wave] + tot_s[wave];
      const int endp = ofs_s[wave] + ((tot_s[wave] + CHUNK - 1) / CHUNK) * CHUNK;
      for (int p = startp + lane; p < endp; p += 64) posrcS[p] = make_int2(-1, 0);
    }
    int running = ofs_s[wave];
#pragma unroll
    for (int ch = 0; ch < CH; ++ch) {
      int inc = v[ch];
#pragma unroll
      for (int off = 1; off < 64; off <<= 1) {
        int n = __shfl_up(inc, off);
        if (lane >= off) inc += n;
      }
      const int b = ch * 64 + lane;
      if (b < EB) blkbaseT[wave * EB + b] = running + inc - v[ch];
      running += __shfl(inc, 63);
    }
  } else {
    constexpr int SEG = NN / 16;          // 3125
    constexpr int CH = (SEG + 63) / 64;   // 49
    __shared__ int wofs[16];
    const int nbase = wave * SEG;
    int v[CH];
#pragma unroll
    for (int ch = 0; ch < CH; ++ch) {
      const int i = ch * 64 + lane;
      v[ch] = (i < SEG) ? degi[nbase + i] : 0;
    }
    {
      int sum = 0;
#pragma unroll
      for (int ch = 0; ch < CH; ++ch) sum += v[ch];
#pragma unroll
      for (int off = 32; off > 0; off >>= 1) sum += __shfl_down(sum, off);
      if (lane == 0) wofs[wave] = sum;
    }
    __syncthreads();
    if (threadIdx.x == 0) {
      int t = 0;
      for (int w2 = 0; w2 < 16; ++w2) { int tv = wofs[w2]; wofs[w2] = t; t += tv; }
    }
    __syncthreads();
    int running = wofs[wave];
#pragma unroll
    for (int ch = 0; ch < CH; ++ch) {
      int inc = v[ch];
#pragma unroll
      for (int off = 1; off < 64; off <<= 1) {
        int n = __shfl_up(inc, off);
        if (lane >= off) inc += n;
      }
      const int i = ch * 64 + lane;
      if (i < SEG) dstbase[nbase + i] = running + inc - v[ch];
      running += __shfl(inc, 63);
    }
  }
}

// Deterministic cell-sorted scatter; recomputes cell+basis from attr.
__global__ __launch_bounds__(256) void scatter_edges(
    const float* __restrict__ attr, const int* __restrict__ blkbaseT,
    const int* __restrict__ srcArr, const int* __restrict__ dstArr,
    const int* __restrict__ dstbase, int* __restrict__ fill2,
    int2* __restrict__ posrcS, f16x4* __restrict__ basS) {
  __shared__ int wc[4][16];
  __shared__ int bs[4][16];
  const int tid = threadIdx.x;
  const int e = blockIdx.x * 256 + tid;
  const float v0 = attr[2 * e] * 4.0f, v1 = attr[2 * e + 1] * 4.0f;
  const float fl0 = floorf(v0), fl1 = floorf(v1);
  const float fr0 = v0 - fl0, fr1 = v1 - fl1;
  const int bx = min(max((int)fl0, 0), 3);
  const int by = min(max((int)fl1, 0), 3);
  const int c = bx + 4 * by;
  const f16x4 bq = {(_Float16)((1.0f - fr0) * (1.0f - fr1)),
                    (_Float16)(fr0 * (1.0f - fr1)),
                    (_Float16)((1.0f - fr0) * fr1),
                    (_Float16)(fr0 * fr1)};
  const int wave = tid >> 6, lane = tid & 63;
  int rank = 0;
#pragma unroll
  for (int k = 0; k < 16; ++k) {
    unsigned long long mm = __ballot(c == k);
    if (k == c) rank = __popcll(mm & ((1ull << lane) - 1ull));
    if (lane == k) wc[wave][k] = __popcll(mm);
  }
  const int d = dstArr[e];
  const int mypos = dstbase[d] + atomicAdd(&fill2[d], 1);
  __syncthreads();
  if (tid < 16) {
    int running = blkbaseT[tid * EB + blockIdx.x];
#pragma unroll
    for (int w = 0; w < 4; ++w) { bs[w][tid] = running; running += wc[w][tid]; }
  }
  __syncthreads();
  const int p = bs[wave][c] + rank;
  posrcS[p] = make_int2(srcArr[e], mypos);
  basS[p] = bq;
}

// ------------------------------------------------- edge msg + root GEMM
// blocks [0, NBLK_EDGE): edge transform; [NBLK_EDGE, NBLK_EDGE+RT_BLK):
// root GEMM rt[n] = xh@root + bias (f16, msg-permuted layout).
template <int IN, bool TWOPASS>
__global__ __launch_bounds__(256) void edge_root(
    const _Float16* __restrict__ xh, const _Float16* __restrict__ wcell,
    const int* __restrict__ chunkcell,
    const int2* __restrict__ posrcS, const f16x4* __restrict__ basS,
    const _Float16* __restrict__ rootT, const float* __restrict__ bias,
    _Float16* __restrict__ rth,
    _Float16* __restrict__ msg, float* __restrict__ agg) {
  constexpr int K = 4 * IN;
  constexpr int KSTEPS = K / 32;
  constexpr int RS = K * 2;            // LDS row stride bytes
  constexpr int OPR = K / 8;           // 16B chunks per row
  constexpr int TILES = CHUNK / 64;    // 4
  constexpr int NCH = (IN == 64) ? 2 : 1;
  __shared__ f16x8 Wt[64 * OPR];
  const int tid = threadIdx.x;
  const int lane = tid & 63;
  const int wave = tid >> 6;
  const int g = lane >> 4, m = lane & 15;
  if (blockIdx.x >= NBLK_EDGE) {       // ---- root GEMM role ----
    constexpr int KS = IN / 32;
    const int base = (blockIdx.x - NBLK_EDGE) * 64 + wave * 16;
    if (base >= NN) return;
    f16x8 bf[KS][4];
#pragma unroll
    for (int ks = 0; ks < KS; ++ks)
#pragma unroll
      for (int nt = 0; nt < 4; ++nt)
        bf[ks][nt] = *reinterpret_cast<const f16x8*>(
            rootT + (size_t)(nt * 16 + m) * IN + ks * 32 + g * 8);
    const int row = base + m;
    f16x8 a[KS];
#pragma unroll
    for (int ks = 0; ks < KS; ++ks)
      a[ks] = *reinterpret_cast<const f16x8*>(xh + (size_t)row * IN + ks * 32 + g * 8);
    f32x4 acc[4];
#pragma unroll
    for (int nt = 0; nt < 4; ++nt) {
      const float fv = bias[nt * 16 + m];
      acc[nt] = (f32x4){fv, fv, fv, fv};
    }
#pragma unroll
    for (int ks = 0; ks < KS; ++ks)
#pragma unroll
      for (int nt = 0; nt < 4; ++nt)
        acc[nt] = __builtin_amdgcn_mfma_f32_16x16x32_f16(a[ks], bf[ks][nt], acc[nt], 0, 0, 0);
#pragma unroll
    for (int r = 0; r < 4; ++r) {
      const int node = base + g * 4 + r;
      f16x4 pv = {(_Float16)acc[0][r], (_Float16)acc[1][r],
                  (_Float16)acc[2][r], (_Float16)acc[3][r]};
      *reinterpret_cast<f16x4*>(rth + (size_t)node * 64 + m * 4) = pv;
    }
    return;
  }
  // ---- edge transform role ----
  const int c = chunkcell[blockIdx.x];
  if (c < 0) return;                   // fully-padded chunk
  const int base = blockIdx.x * CHUNK;
  const int wbase = base + wave * (CHUNK / 4);
  int2 sp_t[TILES];
  f16x4 bas_t[TILES];
#pragma unroll
  for (int t = 0; t < TILES; ++t) sp_t[t] = posrcS[wbase + t * 16 + m];
#pragma unroll
  for (int t = 0; t < TILES; ++t) bas_t[t] = basS[wbase + t * 16 + m];
  {
    const f16x8* gw = reinterpret_cast<const f16x8*>(wcell) + (size_t)c * (64 * OPR);
    for (int o = tid; o < 64 * OPR; o += 256) Wt[o] = gw[o];
  }
  __syncthreads();
  f16x8 xc[TILES][NCH];
#pragma unroll
  for (int t = 0; t < TILES; ++t) {
    const int row = (sp_t[t].x >= 0) ? sp_t[t].x : 0;
    const f16x8* xr = reinterpret_cast<const f16x8*>(xh + (size_t)row * IN);
    xc[t][0] = xr[g];
    if constexpr (IN == 64) xc[t][1] = xr[4 + g];
  }
#pragma unroll
  for (int t = 0; t < TILES; ++t) {
    f32x4 acc[4];
#pragma unroll
    for (int nt = 0; nt < 4; ++nt) acc[nt] = (f32x4){0.f, 0.f, 0.f, 0.f};
#pragma unroll
    for (int ks = 0; ks < KSTEPS; ++ks) {
      const int s = (IN == 64) ? (ks & 3) : ks;
      const f16x8 xin = (IN == 64 && (ks >> 2)) ? xc[t][1] : xc[t][0];
      const f16x8 a = xin * bas_t[t][s];
#pragma unroll
      for (int nt = 0; nt < 4; ++nt) {
        const int n = nt * 16 + m;
        const int byte = n * RS + (((ks * 64) + g * 16) ^ ((n & 15) << 4));
        acc[nt] = __builtin_amdgcn_mfma_f32_16x16x32_f16(a, Wt[byte >> 4], acc[nt], 0, 0, 0);
      }
    }
    // epilogue: D row = edge (lane>>4)*4+r, D col = nt*16 + (lane&15).
    // msg rows PERMUTED (channel nt*16+m at m*4+nt); PLAIN 8B stores so msg
    // retires through L2/L3 and pass2 reads hit the LLC.
#pragma unroll
    for (int r = 0; r < 4; ++r) {
      const int m2 = g * 4 + r;
      const int er = __shfl(sp_t[t].x, m2);
      const int pr = __shfl(sp_t[t].y, m2);
      if (er >= 0) {
        if constexpr (TWOPASS) {
          f16x4 pv = {(_Float16)acc[0][r], (_Float16)acc[1][r],
                      (_Float16)acc[2][r], (_Float16)acc[3][r]};
          *reinterpret_cast<f16x4*>(msg + (size_t)pr * 64 + m * 4) = pv;
        } else {
          float* ap = agg + (size_t)pr * 64 + m;
#pragma unroll
          for (int nt = 0; nt < 4; ++nt) atomicAdd(ap + nt * 16, acc[nt][r]);
        }
      }
    }
  }
}

// --------------------------------------------------------------- pass2
// Pure segment-reduce: xh_out = relu(mean(msg segment) + rt). No LDS/sync.
__global__ __launch_bounds__(256) void pass2_kernel(
    const _Float16* __restrict__ msg, const int* __restrict__ dstbase,
    const int* __restrict__ degi, const _Float16* __restrict__ rth,
    _Float16* __restrict__ xh_out) {
  const int wave = threadIdx.x >> 6, lane = threadIdx.x & 63;
  const int n = blockIdx.x * 4 + wave;   // grid sized so n < NN always
  const int q = lane >> 4, m = lane & 15;
  const _Float16 rv = rth[(size_t)n * 64 + m * 4 + q];  // channel q*16+m
  const int b0 = dstbase[n], dg = degi[n];
  const _Float16* mp = msg + (size_t)b0 * 64 + m * 4;
  float a0 = 0.f, a1 = 0.f, a2 = 0.f, a3 = 0.f;
  const int nfull = dg & ~15;
  int j0 = 0;
  for (; j0 < nfull; j0 += 16) {
    const _Float16* bp = mp + (size_t)j0 * 64;
#pragma unroll
    for (int u = 0; u < 4; ++u) {
      const f16x4 v = *reinterpret_cast<const f16x4*>(bp + (size_t)(u * 4 + q) * 64);
      a0 += (float)v[0]; a1 += (float)v[1]; a2 += (float)v[2]; a3 += (float)v[3];
    }
  }
  if (j0 < dg) {  // masked tail (<16 rows)
#pragma unroll
    for (int u = 0; u < 4; ++u) {
      const int jj = j0 + u * 4 + q;
      const int jc = min(jj, dg - 1);
      const f16x4 v = *reinterpret_cast<const f16x4*>(mp + (size_t)jc * 64);
      const float wv = (jj < dg) ? 1.0f : 0.0f;
      a0 = fmaf(wv, (float)v[0], a0);
      a1 = fmaf(wv, (float)v[1], a1);
      a2 = fmaf(wv, (float)v[2], a2);
      a3 = fmaf(wv, (float)v[3], a3);
    }
  }
  a0 += __shfl_xor(a0, 16); a0 += __shfl_xor(a0, 32);
  a1 += __shfl_xor(a1, 16); a1 += __shfl_xor(a1, 32);
  a2 += __shfl_xor(a2, 16); a2 += __shfl_xor(a2, 32);
  a3 += __shfl_xor(a3, 16); a3 += __shfl_xor(a3, 32);
  const float acc = (q == 0) ? a0 : (q == 1) ? a1 : (q == 2) ? a2 : a3;
  const float r = fmaxf(acc / fmaxf((float)dg, 1.0f) + (float)rv, 0.0f);
  xh_out[(size_t)n * 64 + lane] = (_Float16)r;   // lane == channel q*16+m
}

// --------------------------------------------------------------- finalize
// (atomic-fallback path only)
template <int IN>
__global__ __launch_bounds__(256) void finalize_kernel(
    const _Float16* __restrict__ xh_in, const float* __restrict__ agg,
    const int* __restrict__ degi, const float* __restrict__ root,
    const float* __restrict__ bias, _Float16* __restrict__ xh_out) {
  __shared__ float rl[IN * 64];
  for (int idx = threadIdx.x; idx < IN * 16; idx += 256)
    reinterpret_cast<float4*>(rl)[idx] = reinterpret_cast<const float4*>(root)[idx];
  __syncthreads();
  const int wave = threadIdx.x >> 6, lane = threadIdx.x & 63;
  const int n = blockIdx.x * 4 + wave;
  if (n >= NN) return;
  const float d = fmaxf((float)degi[n], 1.0f);
  float r = agg[(size_t)n * 64 + lane] / d + bias[lane];
  const _Float16* xr = xh_in + (size_t)n * IN;
#pragma unroll 8
  for (int i = 0; i < IN; ++i) r = fmaf((float)xr[i], rl[i * 64 + lane], r);
  r = fmaxf(r, 0.0f);
  xh_out[(size_t)n * 64 + lane] = (_Float16)r;
}

// ------------------------------------------------------------------- output
__global__ __launch_bounds__(256) void out_mfma(
    const _Float16* __restrict__ xh0, const _Float16* __restrict__ xh1,
    const _Float16* __restrict__ xh2, const _Float16* __restrict__ fwT,
    const float* __restrict__ fb, float* __restrict__ out) {
  const int lane = threadIdx.x & 63, wave = threadIdx.x >> 6;
  const int g = lane >> 4, m = lane & 15;
  const int base = blockIdx.x * 64 + wave * 16;   // NN % 16 == 0
  if (base >= NN) return;
  f16x8 bf[5][4];
#pragma unroll
  for (int ks = 0; ks < 5; ++ks)
#pragma unroll
    for (int nt = 0; nt < 4; ++nt)
      bf[ks][nt] = *reinterpret_cast<const f16x8*>(
          fwT + (size_t)(nt * 16 + m) * 160 + ks * 32 + g * 8);
  const int row = base + m;
  f16x8 a[5];
  a[0] = *reinterpret_cast<const f16x8*>(xh0 + (size_t)row * 32 + g * 8);
  a[1] = *reinterpret_cast<const f16x8*>(xh1 + (size_t)row * 64 + g * 8);
  a[2] = *reinterpret_cast<const f16x8*>(xh1 + (size_t)row * 64 + 32 + g * 8);
  a[3] = *reinterpret_cast<const f16x8*>(xh2 + (size_t)row * 64 + g * 8);
  a[4] = *reinterpret_cast<const f16x8*>(xh2 + (size_t)row * 64 + 32 + g * 8);
  f32x4 acc[4];
#pragma unroll
  for (int nt = 0; nt < 4; ++nt) {
    const float fv = fb[nt * 16 + m];
    acc[nt] = (f32x4){fv, fv, fv, fv};
  }
#pragma unroll
  for (int ks = 0; ks < 5; ++ks)
#pragma unroll
    for (int nt = 0; nt < 4; ++nt)
      acc[nt] = __builtin_amdgcn_mfma_f32_16x16x32_f16(a[ks], bf[ks][nt], acc[nt], 0, 0, 0);
#pragma unroll
  for (int r = 0; r < 4; ++r) {
    float* op = out + (size_t)(base + g * 4 + r) * 64 + m;
#pragma unroll
    for (int nt = 0; nt < 4; ++nt) op[nt * 16] = acc[nt][r];
  }
}

extern "C" void kernel_launch(void* const* d_in, const int* in_sizes, int n_in,
                              void* d_out, int out_size, void* d_ws, size_t ws_size,
                              hipStream_t stream) {
  const float* x0 = (const float*)d_in[0];
  const void* eidx = d_in[1];
  const float* attr = (const float*)d_in[2];
  const float* w0 = (const float*)d_in[3];
  const float* root0 = (const float*)d_in[4];
  const float* b0 = (const float*)d_in[5];
  const float* w1 = (const float*)d_in[6];
  const float* root1 = (const float*)d_in[7];
  const float* b1 = (const float*)d_in[8];
  const float* fw = (const float*)d_in[9];
  const float* fb = (const float*)d_in[10];
  float* out = (float*)d_out;
  (void)in_sizes; (void)n_in; (void)out_size;

  char* wsb = (char*)d_ws;
  size_t off = 0;
  auto alloc = [&](size_t bytes) -> void* {
    void* p = wsb + off;
    off += (bytes + 255) & ~(size_t)255;
    return p;
  };
  int* flag = (int*)alloc(256);
  int* src = (int*)alloc(sizeof(int) * EE);
  int* dst = (int*)alloc(sizeof(int) * EE);
  int2* posrcS = (int2*)alloc(sizeof(int2) * ELIST_LEN);
  f16x4* basS = (f16x4*)alloc(sizeof(f16x4) * ELIST_LEN);
  int* chunkcell = (int*)alloc(sizeof(int) * NBLK_EDGE);
  int* degfill = (int*)alloc(sizeof(int) * 2 * NN);   // degi | fill2
  int* degi = degfill;
  int* fill2 = degfill + NN;
  int* dstbase = (int*)alloc(sizeof(int) * NN);
  int* bhT = (int*)alloc(sizeof(int) * EB * 16);
  int* blkbaseT = (int*)alloc(sizeof(int) * EB * 16);
  _Float16* xh0 = (_Float16*)alloc(sizeof(_Float16) * NN * 32);
  _Float16* xh1 = (_Float16*)alloc(sizeof(_Float16) * NN * 64);
  _Float16* xh2 = (_Float16*)alloc(sizeof(_Float16) * NN * 64);
  _Float16* rth = (_Float16*)alloc(sizeof(_Float16) * NN * 64);
  _Float16* wc0 = (_Float16*)alloc(sizeof(_Float16) * 16 * 128 * 64);  // 256KB
  _Float16* wc1 = (_Float16*)alloc(sizeof(_Float16) * 16 * 256 * 64);  // 512KB
  _Float16* fwT = (_Float16*)alloc(sizeof(_Float16) * 64 * 160);
  _Float16* rt0T = (_Float16*)alloc(sizeof(_Float16) * 64 * 32);
  _Float16* rt1T = (_Float16*)alloc(sizeof(_Float16) * 64 * 64);
  const size_t common = off;
  const bool twopass = ws_size >= common + sizeof(_Float16) * (size_t)EE * 64;
  _Float16* msg = nullptr;
  float* agg = nullptr;
  if (twopass) msg = (_Float16*)alloc(sizeof(_Float16) * (size_t)EE * 64);
  else         agg = (float*)alloc(sizeof(float) * (size_t)NN * 64);

  detect_init<<<(2 * NN + 255) / 256, 256, 0, stream>>>(
      (const long long*)eidx, flag, degfill);
  prep_conv<<<EB + CONV_BLK, 256, 0, stream>>>(
      eidx, attr, flag, src, dst, degi, bhT,
      x0, w0, w1, fw, root0, root1, xh0, wc0, wc1, fwT, rt0T, rt1T);
  scan_fused<<<2, 1024, 0, stream>>>(bhT, blkbaseT, chunkcell, posrcS, degi, dstbase);
  scatter_edges<<<EB, 256, 0, stream>>>(attr, blkbaseT, src, dst, dstbase,
                                        fill2, posrcS, basS);

  if (twopass) {
    edge_root<32, true><<<NBLK_EDGE + RT_BLK, 256, 0, stream>>>(
        xh0, wc0, chunkcell, posrcS, basS, rt0T, b0, rth, msg, nullptr);
    pass2_kernel<<<NN / 4, 256, 0, stream>>>(msg, dstbase, degi, rth, xh1);
    edge_root<64, true><<<NBLK_EDGE + RT_BLK, 256, 0, stream>>>(
        xh1, wc1, chunkcell, posrcS, basS, rt1T, b1, rth, msg, nullptr);
    pass2_kernel<<<NN / 4, 256, 0, stream>>>(msg, dstbase, degi, rth, xh2);
  } else {
    hipMemsetAsync(agg, 0, sizeof(float) * NN * 64, stream);
    edge_root<32, false><<<NBLK_EDGE, 256, 0, stream>>>(
        xh0, wc0, chunkcell, posrcS, basS, rt0T, b0, rth, nullptr, agg);
    finalize_kernel<32><<<(NN + 3) / 4, 256, 0, stream>>>(xh0, agg, degi, root0, b0, xh1);
    hipMemsetAsync(agg, 0, sizeof(float) * NN * 64, stream);
    edge_root<64, false><<<NBLK_EDGE, 256, 0, stream>>>(
        xh1, wc1, chunkcell, posrcS, basS, rt1T, b1, rth, nullptr, agg);
    finalize_kernel<64><<<(NN + 3) / 4, 256, 0, stream>>>(xh1, agg, degi, root1, b1, xh2);
  }

  out_mfma<<<(NN + 63) / 64, 256, 0, stream>>>(xh0, xh1, xh2, fwT, fb, out);
}

// Round 14
// 194.058 us; speedup vs baseline: 1.4878x; 1.2134x over previous
//
#include <hip/hip_runtime.h>
#include <hip/hip_bf16.h>
#include <hip/hip_fp16.h>

// SplineCNN forward, MI355X round 14.
// R13 -> R14: the fp16 msg stream was the biggest byte-mover (408MB of the
// ~1GB total). (1) msg now OCP fp8 e4m3 (mean-reduce consumer tolerates the
// 3.5% RMS quantization; threshold headroom 6x) via cvt_pk_fp8_f32 pack /
// cvt_pk_f32_fp8 decode -> 204MB. (2) prep's degi atomicAdd return value is
// the dst-segment rank (rankE) -> scatter loses its 800k-atomic fill2 pass.
// Pre-commit: if absmax > 9.25e-2, revert fp8 next round, keep rankE.

typedef __attribute__((ext_vector_type(8))) _Float16 f16x8;
typedef __attribute__((ext_vector_type(4))) _Float16 f16x4;
typedef __attribute__((ext_vector_type(4))) float f32x4;

constexpr int NN = 50000;       // nodes
constexpr int EE = 800000;      // edges
constexpr int CHUNK = 256;      // edges per block in edge kernels
constexpr int EB = EE / 256;    // 3125 prep/scatter blocks
static_assert(EE % 256 == 0, "prep grid assumes exact divisibility");
constexpr int ELIST_LEN = EE + 16 * CHUNK;
constexpr int NBLK_EDGE = ELIST_LEN / CHUNK;   // 3141
constexpr int RT_BLK = (NN + 63) / 64;         // 782 root-GEMM blocks

// ------------------------------------------------- detect + workspace init
__global__ __launch_bounds__(256) void detect_init(
    const long long* __restrict__ eidx, int* __restrict__ flag,
    int* __restrict__ degi) {
  if (blockIdx.x == 0 && threadIdx.x < 64) {
    long long v = eidx[threadIdx.x];
    bool ok = (v >= 0) && (v < (long long)NN);
    unsigned long long m = __ballot(ok);
    if (threadIdx.x == 0) flag[0] = (m == ~0ull) ? 1 : 0;
  }
  const int i = blockIdx.x * 256 + threadIdx.x;
  if (i < NN) degi[i] = 0;
}

// ------------------------------------------------- prep + one-shot converts
constexpr int F2H_LEN8 = NN * 32 / 8;                 // 200000
constexpr int F2H_BLK = (F2H_LEN8 + 255) / 256;       // 782
constexpr int CW32_BLK = 4 * 16;                      // 64
constexpr int CW64_BLK = 8 * 16;                      // 128
constexpr int CFW_BLK = (64 * 160) / 256;             // 40
constexpr int CRT0_BLK = (64 * 32) / 256;             // 8
constexpr int CRT1_BLK = (64 * 64) / 256;             // 16
constexpr int CONV_BLK = F2H_BLK + CW32_BLK + CW64_BLK + CFW_BLK + CRT0_BLK + CRT1_BLK;

template <int IN>
__device__ __forceinline__ void conv_w_body(
    const float* __restrict__ w, _Float16* __restrict__ wcell, int c, int o) {
  constexpr int K = 4 * IN;
  constexpr int RS = K * 2;
  constexpr int OPR = K / 8;
  const int bx = c & 3, by = c >> 2;
  const int n = o / OPR;
  const int k0 = (o - n * OPR) * 8;
  const int ks = k0 >> 5;
  const int g2 = (k0 & 31) >> 3;
  const int s = (IN == 64) ? (ks & 3) : ks;
  const int i0 = ((IN == 64) ? (ks >> 2) * 32 : 0) + g2 * 8;
  const int kk = (bx + (s & 1)) + 5 * (by + (s >> 1));
  const float* wp = w + ((size_t)kk * IN + i0) * 64 + n;
  f16x8 v;
#pragma unroll
  for (int j = 0; j < 8; ++j) v[j] = (_Float16)wp[(size_t)j * 64];
  const int byte = n * RS + ((k0 * 2) ^ ((n & 15) << 4));
  *reinterpret_cast<f16x8*>(
      reinterpret_cast<char*>(wcell) + (size_t)c * (RS * 64) + byte) = v;
}

// blocks [0,EB): prep (src/dst/rank/deg/cell-hist); rest: converts.
__global__ __launch_bounds__(256) void prep_conv(
    const void* __restrict__ eidx, const float* __restrict__ attr,
    const int* __restrict__ flag,
    int* __restrict__ src, int* __restrict__ dst, int* __restrict__ rankE,
    int* __restrict__ degi, int* __restrict__ bhT,
    const float* __restrict__ x0, const float* __restrict__ w0,
    const float* __restrict__ w1, const float* __restrict__ fw,
    const float* __restrict__ root0, const float* __restrict__ root1,
    _Float16* __restrict__ xh0, _Float16* __restrict__ wc0,
    _Float16* __restrict__ wc1, _Float16* __restrict__ fwT,
    _Float16* __restrict__ rt0T, _Float16* __restrict__ rt1T) {
  __shared__ int wc[4][16];
  const int tid = threadIdx.x;
  if (blockIdx.x < EB) {
    const int e = blockIdx.x * 256 + tid;
    int s, d;
    if (flag[0]) {
      s = (int)((const long long*)eidx)[e];
      d = (int)((const long long*)eidx)[EE + e];
    } else {
      s = ((const int*)eidx)[e];
      d = ((const int*)eidx)[EE + e];
    }
    src[e] = s;
    dst[e] = d;
    rankE[e] = atomicAdd(&degi[d], 1);   // rank within dst segment
    const float v0 = attr[2 * e] * 4.0f, v1 = attr[2 * e + 1] * 4.0f;
    const int bx = min(max((int)floorf(v0), 0), 3);
    const int by = min(max((int)floorf(v1), 0), 3);
    const int c = bx + 4 * by;
    const int wave = tid >> 6, lane = tid & 63;
#pragma unroll
    for (int k = 0; k < 16; ++k) {
      unsigned long long mm = __ballot(c == k);
      if (lane == k) wc[wave][k] = __popcll(mm);
    }
    __syncthreads();
    if (tid < 16)
      bhT[tid * EB + blockIdx.x] = wc[0][tid] + wc[1][tid] + wc[2][tid] + wc[3][tid];
    return;
  }
  const int b = blockIdx.x - EB;
  if (b < F2H_BLK) {
    const int i = b * 256 + tid;
    if (i >= F2H_LEN8) return;
    const float4 a = reinterpret_cast<const float4*>(x0)[i * 2];
    const float4 bb = reinterpret_cast<const float4*>(x0)[i * 2 + 1];
    f16x8 v = {(_Float16)a.x, (_Float16)a.y, (_Float16)a.z, (_Float16)a.w,
               (_Float16)bb.x, (_Float16)bb.y, (_Float16)bb.z, (_Float16)bb.w};
    reinterpret_cast<f16x8*>(xh0)[i] = v;
  } else if (b < F2H_BLK + CW32_BLK) {
    const int r = b - F2H_BLK;
    conv_w_body<32>(w0, wc0, r >> 2, (r & 3) * 256 + tid);
  } else if (b < F2H_BLK + CW32_BLK + CW64_BLK) {
    const int r = b - F2H_BLK - CW32_BLK;
    conv_w_body<64>(w1, wc1, r >> 3, (r & 7) * 256 + tid);
  } else if (b < F2H_BLK + CW32_BLK + CW64_BLK + CFW_BLK) {
    const int i = (b - F2H_BLK - CW32_BLK - CW64_BLK) * 256 + tid;  // < 10240
    const int n = i / 160, k = i - n * 160;
    fwT[i] = (_Float16)fw[k * 64 + n];
  } else if (b < F2H_BLK + CW32_BLK + CW64_BLK + CFW_BLK + CRT0_BLK) {
    const int i = (b - F2H_BLK - CW32_BLK - CW64_BLK - CFW_BLK) * 256 + tid;
    const int n = i / 32, k = i - n * 32;   // i < 2048
    rt0T[i] = (_Float16)root0[k * 64 + n];
  } else {
    const int i = (b - F2H_BLK - CW32_BLK - CW64_BLK - CFW_BLK - CRT0_BLK) * 256 + tid;
    const int n = i / 64, k = i - n * 64;   // i < 4096
    rt1T[i] = (_Float16)root1[k * 64 + n];
  }
}

// --------------------------------------------------------------- fused scans
__global__ __launch_bounds__(1024) void scan_fused(
    const int* __restrict__ bhT, int* __restrict__ blkbaseT,
    int* __restrict__ chunkcell, int2* __restrict__ posrcS,
    const int* __restrict__ degi, int* __restrict__ dstbase) {
  const int wave = threadIdx.x >> 6, lane = threadIdx.x & 63;
  if (blockIdx.x == 0) {
    constexpr int CH = (EB + 63) / 64;   // 49
    __shared__ int ofs_s[16];
    __shared__ int tot_s[16];
    int v[CH];
#pragma unroll
    for (int ch = 0; ch < CH; ++ch) {
      const int b = ch * 64 + lane;
      v[ch] = (b < EB) ? bhT[wave * EB + b] : 0;
    }
    {
      int sum = 0;
#pragma unroll
      for (int ch = 0; ch < CH; ++ch) sum += v[ch];
#pragma unroll
      for (int off = 32; off > 0; off >>= 1) sum += __shfl_down(sum, off);
      if (lane == 0) tot_s[wave] = sum;
    }
    __syncthreads();
    if (threadIdx.x == 0) {
      int t = 0;
      for (int c = 0; c < 16; ++c) {
        ofs_s[c] = t;
        t += ((tot_s[c] + CHUNK - 1) / CHUNK) * CHUNK;
      }
    }
    __syncthreads();
    {  // chunk -> cell map; padding chunks get -1
      const int nch = (tot_s[wave] + CHUNK - 1) / CHUNK;
      const int cb = ofs_s[wave] / CHUNK;
      for (int i = lane; i < nch; i += 64) chunkcell[cb + i] = wave;
      if (wave == 15) {
        const int totch = cb + nch;
        for (int i = totch + lane; i < NBLK_EDGE; i += 64) chunkcell[i] = -1;
      }
    }
    {  // pad sentinels for this cell's segment
      const int startp = ofs_s[wave] + tot_s[wave];
      const int endp = ofs_s[wave] + ((tot_s[wave] + CHUNK - 1) / CHUNK) * CHUNK;
      for (int p = startp + lane; p < endp; p += 64) posrcS[p] = make_int2(-1, 0);
    }
    int running = ofs_s[wave];
#pragma unroll
    for (int ch = 0; ch < CH; ++ch) {
      int inc = v[ch];
#pragma unroll
      for (int off = 1; off < 64; off <<= 1) {
        int n = __shfl_up(inc, off);
        if (lane >= off) inc += n;
      }
      const int b = ch * 64 + lane;
      if (b < EB) blkbaseT[wave * EB + b] = running + inc - v[ch];
      running += __shfl(inc, 63);
    }
  } else {
    constexpr int SEG = NN / 16;          // 3125
    constexpr int CH = (SEG + 63) / 64;   // 49
    __shared__ int wofs[16];
    const int nbase = wave * SEG;
    int v[CH];
#pragma unroll
    for (int ch = 0; ch < CH; ++ch) {
      const int i = ch * 64 + lane;
      v[ch] = (i < SEG) ? degi[nbase + i] : 0;
    }
    {
      int sum = 0;
#pragma unroll
      for (int ch = 0; ch < CH; ++ch) sum += v[ch];
#pragma unroll
      for (int off = 32; off > 0; off >>= 1) sum += __shfl_down(sum, off);
      if (lane == 0) wofs[wave] = sum;
    }
    __syncthreads();
    if (threadIdx.x == 0) {
      int t = 0;
      for (int w2 = 0; w2 < 16; ++w2) { int tv = wofs[w2]; wofs[w2] = t; t += tv; }
    }
    __syncthreads();
    int running = wofs[wave];
#pragma unroll
    for (int ch = 0; ch < CH; ++ch) {
      int inc = v[ch];
#pragma unroll
      for (int off = 1; off < 64; off <<= 1) {
        int n = __shfl_up(inc, off);
        if (lane >= off) inc += n;
      }
      const int i = ch * 64 + lane;
      if (i < SEG) dstbase[nbase + i] = running + inc - v[ch];
      running += __shfl(inc, 63);
    }
  }
}

// Deterministic cell-sorted scatter; basis from attr; pos = dstbase + rankE
// (no atomics here anymore).
__global__ __launch_bounds__(256) void scatter_edges(
    const float* __restrict__ attr, const int* __restrict__ blkbaseT,
    const int* __restrict__ srcArr, const int* __restrict__ dstArr,
    const int* __restrict__ rankE, const int* __restrict__ dstbase,
    int2* __restrict__ posrcS, f16x4* __restrict__ basS) {
  __shared__ int wc[4][16];
  __shared__ int bs[4][16];
  const int tid = threadIdx.x;
  const int e = blockIdx.x * 256 + tid;
  const float v0 = attr[2 * e] * 4.0f, v1 = attr[2 * e + 1] * 4.0f;
  const float fl0 = floorf(v0), fl1 = floorf(v1);
  const float fr0 = v0 - fl0, fr1 = v1 - fl1;
  const int bx = min(max((int)fl0, 0), 3);
  const int by = min(max((int)fl1, 0), 3);
  const int c = bx + 4 * by;
  const f16x4 bq = {(_Float16)((1.0f - fr0) * (1.0f - fr1)),
                    (_Float16)(fr0 * (1.0f - fr1)),
                    (_Float16)((1.0f - fr0) * fr1),
                    (_Float16)(fr0 * fr1)};
  const int wave = tid >> 6, lane = tid & 63;
  int rank = 0;
#pragma unroll
  for (int k = 0; k < 16; ++k) {
    unsigned long long mm = __ballot(c == k);
    if (k == c) rank = __popcll(mm & ((1ull << lane) - 1ull));
    if (lane == k) wc[wave][k] = __popcll(mm);
  }
  const int mypos = dstbase[dstArr[e]] + rankE[e];
  __syncthreads();
  if (tid < 16) {
    int running = blkbaseT[tid * EB + blockIdx.x];
#pragma unroll
    for (int w = 0; w < 4; ++w) { bs[w][tid] = running; running += wc[w][tid]; }
  }
  __syncthreads();
  const int p = bs[wave][c] + rank;
  posrcS[p] = make_int2(srcArr[e], mypos);
  basS[p] = bq;
}

// ------------------------------------------------- edge msg + root GEMM
// blocks [0, NBLK_EDGE): edge transform (msg in fp8 e4m3, permuted rows);
// [NBLK_EDGE, ...): root GEMM rt[n] = xh@root + bias (f16, permuted layout).
template <int IN, bool TWOPASS>
__global__ __launch_bounds__(256) void edge_root(
    const _Float16* __restrict__ xh, const _Float16* __restrict__ wcell,
    const int* __restrict__ chunkcell,
    const int2* __restrict__ posrcS, const f16x4* __restrict__ basS,
    const _Float16* __restrict__ rootT, const float* __restrict__ bias,
    _Float16* __restrict__ rth,
    unsigned char* __restrict__ msg, float* __restrict__ agg) {
  constexpr int K = 4 * IN;
  constexpr int KSTEPS = K / 32;
  constexpr int RS = K * 2;            // LDS row stride bytes
  constexpr int OPR = K / 8;           // 16B chunks per row
  constexpr int TILES = CHUNK / 64;    // 4
  constexpr int NCH = (IN == 64) ? 2 : 1;
  __shared__ f16x8 Wt[64 * OPR];
  const int tid = threadIdx.x;
  const int lane = tid & 63;
  const int wave = tid >> 6;
  const int g = lane >> 4, m = lane & 15;
  if (blockIdx.x >= NBLK_EDGE) {       // ---- root GEMM role ----
    constexpr int KS = IN / 32;
    const int base = (blockIdx.x - NBLK_EDGE) * 64 + wave * 16;
    if (base >= NN) return;
    f16x8 bf[KS][4];
#pragma unroll
    for (int ks = 0; ks < KS; ++ks)
#pragma unroll
      for (int nt = 0; nt < 4; ++nt)
        bf[ks][nt] = *reinterpret_cast<const f16x8*>(
            rootT + (size_t)(nt * 16 + m) * IN + ks * 32 + g * 8);
    const int row = base + m;
    f16x8 a[KS];
#pragma unroll
    for (int ks = 0; ks < KS; ++ks)
      a[ks] = *reinterpret_cast<const f16x8*>(xh + (size_t)row * IN + ks * 32 + g * 8);
    f32x4 acc[4];
#pragma unroll
    for (int nt = 0; nt < 4; ++nt) {
      const float fv = bias[nt * 16 + m];
      acc[nt] = (f32x4){fv, fv, fv, fv};
    }
#pragma unroll
    for (int ks = 0; ks < KS; ++ks)
#pragma unroll
      for (int nt = 0; nt < 4; ++nt)
        acc[nt] = __builtin_amdgcn_mfma_f32_16x16x32_f16(a[ks], bf[ks][nt], acc[nt], 0, 0, 0);
#pragma unroll
    for (int r = 0; r < 4; ++r) {
      const int node = base + g * 4 + r;
      f16x4 pv = {(_Float16)acc[0][r], (_Float16)acc[1][r],
                  (_Float16)acc[2][r], (_Float16)acc[3][r]};
      *reinterpret_cast<f16x4*>(rth + (size_t)node * 64 + m * 4) = pv;
    }
    return;
  }
  // ---- edge transform role ----
  const int c = chunkcell[blockIdx.x];
  if (c < 0) return;                   // fully-padded chunk
  const int base = blockIdx.x * CHUNK;
  const int wbase = base + wave * (CHUNK / 4);
  int2 sp_t[TILES];
  f16x4 bas_t[TILES];
#pragma unroll
  for (int t = 0; t < TILES; ++t) sp_t[t] = posrcS[wbase + t * 16 + m];
#pragma unroll
  for (int t = 0; t < TILES; ++t) bas_t[t] = basS[wbase + t * 16 + m];
  {
    const f16x8* gw = reinterpret_cast<const f16x8*>(wcell) + (size_t)c * (64 * OPR);
    for (int o = tid; o < 64 * OPR; o += 256) Wt[o] = gw[o];
  }
  __syncthreads();
  f16x8 xc[TILES][NCH];
#pragma unroll
  for (int t = 0; t < TILES; ++t) {
    const int row = (sp_t[t].x >= 0) ? sp_t[t].x : 0;
    const f16x8* xr = reinterpret_cast<const f16x8*>(xh + (size_t)row * IN);
    xc[t][0] = xr[g];
    if constexpr (IN == 64) xc[t][1] = xr[4 + g];
  }
#pragma unroll
  for (int t = 0; t < TILES; ++t) {
    f32x4 acc[4];
#pragma unroll
    for (int nt = 0; nt < 4; ++nt) acc[nt] = (f32x4){0.f, 0.f, 0.f, 0.f};
#pragma unroll
    for (int ks = 0; ks < KSTEPS; ++ks) {
      const int s = (IN == 64) ? (ks & 3) : ks;
      const f16x8 xin = (IN == 64 && (ks >> 2)) ? xc[t][1] : xc[t][0];
      const f16x8 a = xin * bas_t[t][s];
#pragma unroll
      for (int nt = 0; nt < 4; ++nt) {
        const int n = nt * 16 + m;
        const int byte = n * RS + (((ks * 64) + g * 16) ^ ((n & 15) << 4));
        acc[nt] = __builtin_amdgcn_mfma_f32_16x16x32_f16(a, Wt[byte >> 4], acc[nt], 0, 0, 0);
      }
    }
    // epilogue: D row = edge (lane>>4)*4+r, D col = nt*16 + (lane&15).
    // fp8 msg rows (64B): channel nt*16+m at byte m*4+nt; for fixed r the 16
    // lanes of a group cover one full 64B row (fully-written lines).
#pragma unroll
    for (int r = 0; r < 4; ++r) {
      const int m2 = g * 4 + r;
      const int er = __shfl(sp_t[t].x, m2);
      const int pr = __shfl(sp_t[t].y, m2);
      if (er >= 0) {
        if constexpr (TWOPASS) {
          unsigned int p8 = __builtin_amdgcn_cvt_pk_fp8_f32(acc[0][r], acc[1][r], 0u, false);
          p8 = __builtin_amdgcn_cvt_pk_fp8_f32(acc[2][r], acc[3][r], p8, true);
          *reinterpret_cast<unsigned int*>(msg + (size_t)pr * 64 + m * 4) = p8;
        } else {
          float* ap = agg + (size_t)pr * 64 + m;
#pragma unroll
          for (int nt = 0; nt < 4; ++nt) atomicAdd(ap + nt * 16, acc[nt][r]);
        }
      }
    }
  }
}

// --------------------------------------------------------------- pass2
// Pure segment-reduce over fp8 msg: xh_out = relu(mean + rt). No LDS/sync.
// Lane group q reads 4B (4 fp8 ch) per row, 16 rows in flight; shfl_xor
// combines groups; decode via cvt_pk_f32_fp8.
__global__ __launch_bounds__(256) void pass2_kernel(
    const unsigned char* __restrict__ msg, const int* __restrict__ dstbase,
    const int* __restrict__ degi, const _Float16* __restrict__ rth,
    _Float16* __restrict__ xh_out) {
  const int wave = threadIdx.x >> 6, lane = threadIdx.x & 63;
  const int n = blockIdx.x * 4 + wave;   // grid sized so n < NN always
  const int q = lane >> 4, m = lane & 15;
  const _Float16 rv = rth[(size_t)n * 64 + m * 4 + q];  // channel q*16+m
  const int b0 = dstbase[n], dg = degi[n];
  const unsigned int* mp =
      reinterpret_cast<const unsigned int*>(msg + (size_t)b0 * 64 + m * 4);
  float a0 = 0.f, a1 = 0.f, a2 = 0.f, a3 = 0.f;
  const int nfull = dg & ~15;
  int j0 = 0;
  for (; j0 < nfull; j0 += 16) {
    const unsigned int* bp = mp + (size_t)j0 * 16;   // row stride = 16 uints
#pragma unroll
    for (int u = 0; u < 4; ++u) {
      const unsigned int pw = bp[(size_t)(u * 4 + q) * 16];
      const auto lo = __builtin_amdgcn_cvt_pk_f32_fp8(pw, false);
      const auto hi = __builtin_amdgcn_cvt_pk_f32_fp8(pw, true);
      a0 += lo[0]; a1 += lo[1]; a2 += hi[0]; a3 += hi[1];
    }
  }
  if (j0 < dg) {  // masked tail (<16 rows)
#pragma unroll
    for (int u = 0; u < 4; ++u) {
      const int jj = j0 + u * 4 + q;
      const int jc = min(jj, dg - 1);
      const unsigned int pw = mp[(size_t)jc * 16];
      const auto lo = __builtin_amdgcn_cvt_pk_f32_fp8(pw, false);
      const auto hi = __builtin_amdgcn_cvt_pk_f32_fp8(pw, true);
      const float wv = (jj < dg) ? 1.0f : 0.0f;
      a0 = fmaf(wv, lo[0], a0);
      a1 = fmaf(wv, lo[1], a1);
      a2 = fmaf(wv, hi[0], a2);
      a3 = fmaf(wv, hi[1], a3);
    }
  }
  a0 += __shfl_xor(a0, 16); a0 += __shfl_xor(a0, 32);
  a1 += __shfl_xor(a1, 16); a1 += __shfl_xor(a1, 32);
  a2 += __shfl_xor(a2, 16); a2 += __shfl_xor(a2, 32);
  a3 += __shfl_xor(a3, 16); a3 += __shfl_xor(a3, 32);
  const float acc = (q == 0) ? a0 : (q == 1) ? a1 : (q == 2) ? a2 : a3;
  const float r = fmaxf(acc / fmaxf((float)dg, 1.0f) + (float)rv, 0.0f);
  xh_out[(size_t)n * 64 + lane] = (_Float16)r;   // lane == channel q*16+m
}

// --------------------------------------------------------------- finalize
// (atomic-fallback path only)
template <int IN>
__global__ __launch_bounds__(256) void finalize_kernel(
    const _Float16* __restrict__ xh_in, const float* __restrict__ agg,
    const int* __restrict__ degi, const float* __restrict__ root,
    const float* __restrict__ bias, _Float16* __restrict__ xh_out) {
  __shared__ float rl[IN * 64];
  for (int idx = threadIdx.x; idx < IN * 16; idx += 256)
    reinterpret_cast<float4*>(rl)[idx] = reinterpret_cast<const float4*>(root)[idx];
  __syncthreads();
  const int wave = threadIdx.x >> 6, lane = threadIdx.x & 63;
  const int n = blockIdx.x * 4 + wave;
  if (n >= NN) return;
  const float d = fmaxf((float)degi[n], 1.0f);
  float r = agg[(size_t)n * 64 + lane] / d + bias[lane];
  const _Float16* xr = xh_in + (size_t)n * IN;
#pragma unroll 8
  for (int i = 0; i < IN; ++i) r = fmaf((float)xr[i], rl[i * 64 + lane], r);
  r = fmaxf(r, 0.0f);
  xh_out[(size_t)n * 64 + lane] = (_Float16)r;
}

// ------------------------------------------------------------------- output
__global__ __launch_bounds__(256) void out_mfma(
    const _Float16* __restrict__ xh0, const _Float16* __restrict__ xh1,
    const _Float16* __restrict__ xh2, const _Float16* __restrict__ fwT,
    const float* __restrict__ fb, float* __restrict__ out) {
  const int lane = threadIdx.x & 63, wave = threadIdx.x >> 6;
  const int g = lane >> 4, m = lane & 15;
  const int base = blockIdx.x * 64 + wave * 16;   // NN % 16 == 0
  if (base >= NN) return;
  f16x8 bf[5][4];
#pragma unroll
  for (int ks = 0; ks < 5; ++ks)
#pragma unroll
    for (int nt = 0; nt < 4; ++nt)
      bf[ks][nt] = *reinterpret_cast<const f16x8*>(
          fwT + (size_t)(nt * 16 + m) * 160 + ks * 32 + g * 8);
  const int row = base + m;
  f16x8 a[5];
  a[0] = *reinterpret_cast<const f16x8*>(xh0 + (size_t)row * 32 + g * 8);
  a[1] = *reinterpret_cast<const f16x8*>(xh1 + (size_t)row * 64 + g * 8);
  a[2] = *reinterpret_cast<const f16x8*>(xh1 + (size_t)row * 64 + 32 + g * 8);
  a[3] = *reinterpret_cast<const f16x8*>(xh2 + (size_t)row * 64 + g * 8);
  a[4] = *reinterpret_cast<const f16x8*>(xh2 + (size_t)row * 64 + 32 + g * 8);
  f32x4 acc[4];
#pragma unroll
  for (int nt = 0; nt < 4; ++nt) {
    const float fv = fb[nt * 16 + m];
    acc[nt] = (f32x4){fv, fv, fv, fv};
  }
#pragma unroll
  for (int ks = 0; ks < 5; ++ks)
#pragma unroll
    for (int nt = 0; nt < 4; ++nt)
      acc[nt] = __builtin_amdgcn_mfma_f32_16x16x32_f16(a[ks], bf[ks][nt], acc[nt], 0, 0, 0);
#pragma unroll
  for (int r = 0; r < 4; ++r) {
    float* op = out + (size_t)(base + g * 4 + r) * 64 + m;
#pragma unroll
    for (int nt = 0; nt < 4; ++nt) op[nt * 16] = acc[nt][r];
  }
}

extern "C" void kernel_launch(void* const* d_in, const int* in_sizes, int n_in,
                              void* d_out, int out_size, void* d_ws, size_t ws_size,
                              hipStream_t stream) {
  const float* x0 = (const float*)d_in[0];
  const void* eidx = d_in[1];
  const float* attr = (const float*)d_in[2];
  const float* w0 = (const float*)d_in[3];
  const float* root0 = (const float*)d_in[4];
  const float* b0 = (const float*)d_in[5];
  const float* w1 = (const float*)d_in[6];
  const float* root1 = (const float*)d_in[7];
  const float* b1 = (const float*)d_in[8];
  const float* fw = (const float*)d_in[9];
  const float* fb = (const float*)d_in[10];
  float* out = (float*)d_out;
  (void)in_sizes; (void)n_in; (void)out_size;

  char* wsb = (char*)d_ws;
  size_t off = 0;
  auto alloc = [&](size_t bytes) -> void* {
    void* p = wsb + off;
    off += (bytes + 255) & ~(size_t)255;
    return p;
  };
  int* flag = (int*)alloc(256);
  int* src = (int*)alloc(sizeof(int) * EE);
  int* dst = (int*)alloc(sizeof(int) * EE);
  int* rankE = (int*)alloc(sizeof(int) * EE);
  int2* posrcS = (int2*)alloc(sizeof(int2) * ELIST_LEN);
  f16x4* basS = (f16x4*)alloc(sizeof(f16x4) * ELIST_LEN);
  int* chunkcell = (int*)alloc(sizeof(int) * NBLK_EDGE);
  int* degi = (int*)alloc(sizeof(int) * NN);
  int* dstbase = (int*)alloc(sizeof(int) * NN);
  int* bhT = (int*)alloc(sizeof(int) * EB * 16);
  int* blkbaseT = (int*)alloc(sizeof(int) * EB * 16);
  _Float16* xh0 = (_Float16*)alloc(sizeof(_Float16) * NN * 32);
  _Float16* xh1 = (_Float16*)alloc(sizeof(_Float16) * NN * 64);
  _Float16* xh2 = (_Float16*)alloc(sizeof(_Float16) * NN * 64);
  _Float16* rth = (_Float16*)alloc(sizeof(_Float16) * NN * 64);
  _Float16* wc0 = (_Float16*)alloc(sizeof(_Float16) * 16 * 128 * 64);  // 256KB
  _Float16* wc1 = (_Float16*)alloc(sizeof(_Float16) * 16 * 256 * 64);  // 512KB
  _Float16* fwT = (_Float16*)alloc(sizeof(_Float16) * 64 * 160);
  _Float16* rt0T = (_Float16*)alloc(sizeof(_Float16) * 64 * 32);
  _Float16* rt1T = (_Float16*)alloc(sizeof(_Float16) * 64 * 64);
  const size_t common = off;
  const bool twopass = ws_size >= common + (size_t)EE * 64;  // fp8 msg: 51.2MB
  unsigned char* msg = nullptr;
  float* agg = nullptr;
  if (twopass) msg = (unsigned char*)alloc((size_t)EE * 64);
  else         agg = (float*)alloc(sizeof(float) * (size_t)NN * 64);

  detect_init<<<(NN + 255) / 256, 256, 0, stream>>>(
      (const long long*)eidx, flag, degi);
  prep_conv<<<EB + CONV_BLK, 256, 0, stream>>>(
      eidx, attr, flag, src, dst, rankE, degi, bhT,
      x0, w0, w1, fw, root0, root1, xh0, wc0, wc1, fwT, rt0T, rt1T);
  scan_fused<<<2, 1024, 0, stream>>>(bhT, blkbaseT, chunkcell, posrcS, degi, dstbase);
  scatter_edges<<<EB, 256, 0, stream>>>(attr, blkbaseT, src, dst, rankE, dstbase,
                                        posrcS, basS);

  if (twopass) {
    edge_root<32, true><<<NBLK_EDGE + RT_BLK, 256, 0, stream>>>(
        xh0, wc0, chunkcell, posrcS, basS, rt0T, b0, rth, msg, nullptr);
    pass2_kernel<<<NN / 4, 256, 0, stream>>>(msg, dstbase, degi, rth, xh1);
    edge_root<64, true><<<NBLK_EDGE + RT_BLK, 256, 0, stream>>>(
        xh1, wc1, chunkcell, posrcS, basS, rt1T, b1, rth, msg, nullptr);
    pass2_kernel<<<NN / 4, 256, 0, stream>>>(msg, dstbase, degi, rth, xh2);
  } else {
    hipMemsetAsync(agg, 0, sizeof(float) * NN * 64, stream);
    edge_root<32, false><<<NBLK_EDGE, 256, 0, stream>>>(
        xh0, wc0, chunkcell, posrcS, basS, rt0T, b0, rth, nullptr, agg);
    finalize_kernel<32><<<(NN + 3) / 4, 256, 0, stream>>>(xh0, agg, degi, root0, b0, xh1);
    hipMemsetAsync(agg, 0, sizeof(float) * NN * 64, stream);
    edge_root<64, false><<<NBLK_EDGE, 256, 0, stream>>>(
        xh1, wc1, chunkcell, posrcS, basS, rt1T, b1, rth, nullptr, agg);
    finalize_kernel<64><<<(NN + 3) / 4, 256, 0, stream>>>(xh1, agg, degi, root1, b1, xh2);
  }

  out_mfma<<<(NN + 63) / 64, 256, 0, stream>>>(xh0, xh1, xh2, fwT, fb, out);
}

// Round 15
// 185.741 us; speedup vs baseline: 1.5544x; 1.0448x over previous
//
#include <hip/hip_runtime.h>
#include <hip/hip_bf16.h>
#include <hip/hip_fp16.h>

// SplineCNN forward, MI355X round 15.
// R14 -> R15: edge kernels were LDS-read-throughput bound: 128 ds_read_b128
// per wave (B re-read per M-tile) at ~12cyc vs 128 MFMA at ~5cyc. Loop nest
// reordered to per-ks/per-nt { one B read -> 4 MFMAs (4 tiles) }: LDS reads
// 128 -> 32 per wave, MFMA becomes the critical pipe. acc now [4][4] f32x4
// (+48 VGPR, fully static-indexed).

typedef __attribute__((ext_vector_type(8))) _Float16 f16x8;
typedef __attribute__((ext_vector_type(4))) _Float16 f16x4;
typedef __attribute__((ext_vector_type(4))) float f32x4;

constexpr int NN = 50000;       // nodes
constexpr int EE = 800000;      // edges
constexpr int CHUNK = 256;      // edges per block in edge kernels
constexpr int EB = EE / 256;    // 3125 prep/scatter blocks
static_assert(EE % 256 == 0, "prep grid assumes exact divisibility");
constexpr int ELIST_LEN = EE + 16 * CHUNK;
constexpr int NBLK_EDGE = ELIST_LEN / CHUNK;   // 3141
constexpr int RT_BLK = (NN + 63) / 64;         // 782 root-GEMM blocks

// ------------------------------------------------- detect + workspace init
__global__ __launch_bounds__(256) void detect_init(
    const long long* __restrict__ eidx, int* __restrict__ flag,
    int* __restrict__ degi) {
  if (blockIdx.x == 0 && threadIdx.x < 64) {
    long long v = eidx[threadIdx.x];
    bool ok = (v >= 0) && (v < (long long)NN);
    unsigned long long m = __ballot(ok);
    if (threadIdx.x == 0) flag[0] = (m == ~0ull) ? 1 : 0;
  }
  const int i = blockIdx.x * 256 + threadIdx.x;
  if (i < NN) degi[i] = 0;
}

// ------------------------------------------------- prep + one-shot converts
constexpr int F2H_LEN8 = NN * 32 / 8;                 // 200000
constexpr int F2H_BLK = (F2H_LEN8 + 255) / 256;       // 782
constexpr int CW32_BLK = 4 * 16;                      // 64
constexpr int CW64_BLK = 8 * 16;                      // 128
constexpr int CFW_BLK = (64 * 160) / 256;             // 40
constexpr int CRT0_BLK = (64 * 32) / 256;             // 8
constexpr int CRT1_BLK = (64 * 64) / 256;             // 16
constexpr int CONV_BLK = F2H_BLK + CW32_BLK + CW64_BLK + CFW_BLK + CRT0_BLK + CRT1_BLK;

template <int IN>
__device__ __forceinline__ void conv_w_body(
    const float* __restrict__ w, _Float16* __restrict__ wcell, int c, int o) {
  constexpr int K = 4 * IN;
  constexpr int RS = K * 2;
  constexpr int OPR = K / 8;
  const int bx = c & 3, by = c >> 2;
  const int n = o / OPR;
  const int k0 = (o - n * OPR) * 8;
  const int ks = k0 >> 5;
  const int g2 = (k0 & 31) >> 3;
  const int s = (IN == 64) ? (ks & 3) : ks;
  const int i0 = ((IN == 64) ? (ks >> 2) * 32 : 0) + g2 * 8;
  const int kk = (bx + (s & 1)) + 5 * (by + (s >> 1));
  const float* wp = w + ((size_t)kk * IN + i0) * 64 + n;
  f16x8 v;
#pragma unroll
  for (int j = 0; j < 8; ++j) v[j] = (_Float16)wp[(size_t)j * 64];
  const int byte = n * RS + ((k0 * 2) ^ ((n & 15) << 4));
  *reinterpret_cast<f16x8*>(
      reinterpret_cast<char*>(wcell) + (size_t)c * (RS * 64) + byte) = v;
}

// blocks [0,EB): prep (src/dst/rank/deg/cell-hist); rest: converts.
__global__ __launch_bounds__(256) void prep_conv(
    const void* __restrict__ eidx, const float* __restrict__ attr,
    const int* __restrict__ flag,
    int* __restrict__ src, int* __restrict__ dst, int* __restrict__ rankE,
    int* __restrict__ degi, int* __restrict__ bhT,
    const float* __restrict__ x0, const float* __restrict__ w0,
    const float* __restrict__ w1, const float* __restrict__ fw,
    const float* __restrict__ root0, const float* __restrict__ root1,
    _Float16* __restrict__ xh0, _Float16* __restrict__ wc0,
    _Float16* __restrict__ wc1, _Float16* __restrict__ fwT,
    _Float16* __restrict__ rt0T, _Float16* __restrict__ rt1T) {
  __shared__ int wc[4][16];
  const int tid = threadIdx.x;
  if (blockIdx.x < EB) {
    const int e = blockIdx.x * 256 + tid;
    int s, d;
    if (flag[0]) {
      s = (int)((const long long*)eidx)[e];
      d = (int)((const long long*)eidx)[EE + e];
    } else {
      s = ((const int*)eidx)[e];
      d = ((const int*)eidx)[EE + e];
    }
    src[e] = s;
    dst[e] = d;
    rankE[e] = atomicAdd(&degi[d], 1);   // rank within dst segment
    const float v0 = attr[2 * e] * 4.0f, v1 = attr[2 * e + 1] * 4.0f;
    const int bx = min(max((int)floorf(v0), 0), 3);
    const int by = min(max((int)floorf(v1), 0), 3);
    const int c = bx + 4 * by;
    const int wave = tid >> 6, lane = tid & 63;
#pragma unroll
    for (int k = 0; k < 16; ++k) {
      unsigned long long mm = __ballot(c == k);
      if (lane == k) wc[wave][k] = __popcll(mm);
    }
    __syncthreads();
    if (tid < 16)
      bhT[tid * EB + blockIdx.x] = wc[0][tid] + wc[1][tid] + wc[2][tid] + wc[3][tid];
    return;
  }
  const int b = blockIdx.x - EB;
  if (b < F2H_BLK) {
    const int i = b * 256 + tid;
    if (i >= F2H_LEN8) return;
    const float4 a = reinterpret_cast<const float4*>(x0)[i * 2];
    const float4 bb = reinterpret_cast<const float4*>(x0)[i * 2 + 1];
    f16x8 v = {(_Float16)a.x, (_Float16)a.y, (_Float16)a.z, (_Float16)a.w,
               (_Float16)bb.x, (_Float16)bb.y, (_Float16)bb.z, (_Float16)bb.w};
    reinterpret_cast<f16x8*>(xh0)[i] = v;
  } else if (b < F2H_BLK + CW32_BLK) {
    const int r = b - F2H_BLK;
    conv_w_body<32>(w0, wc0, r >> 2, (r & 3) * 256 + tid);
  } else if (b < F2H_BLK + CW32_BLK + CW64_BLK) {
    const int r = b - F2H_BLK - CW32_BLK;
    conv_w_body<64>(w1, wc1, r >> 3, (r & 7) * 256 + tid);
  } else if (b < F2H_BLK + CW32_BLK + CW64_BLK + CFW_BLK) {
    const int i = (b - F2H_BLK - CW32_BLK - CW64_BLK) * 256 + tid;  // < 10240
    const int n = i / 160, k = i - n * 160;
    fwT[i] = (_Float16)fw[k * 64 + n];
  } else if (b < F2H_BLK + CW32_BLK + CW64_BLK + CFW_BLK + CRT0_BLK) {
    const int i = (b - F2H_BLK - CW32_BLK - CW64_BLK - CFW_BLK) * 256 + tid;
    const int n = i / 32, k = i - n * 32;   // i < 2048
    rt0T[i] = (_Float16)root0[k * 64 + n];
  } else {
    const int i = (b - F2H_BLK - CW32_BLK - CW64_BLK - CFW_BLK - CRT0_BLK) * 256 + tid;
    const int n = i / 64, k = i - n * 64;   // i < 4096
    rt1T[i] = (_Float16)root1[k * 64 + n];
  }
}

// --------------------------------------------------------------- fused scans
__global__ __launch_bounds__(1024) void scan_fused(
    const int* __restrict__ bhT, int* __restrict__ blkbaseT,
    int* __restrict__ chunkcell, int2* __restrict__ posrcS,
    const int* __restrict__ degi, int* __restrict__ dstbase) {
  const int wave = threadIdx.x >> 6, lane = threadIdx.x & 63;
  if (blockIdx.x == 0) {
    constexpr int CH = (EB + 63) / 64;   // 49
    __shared__ int ofs_s[16];
    __shared__ int tot_s[16];
    int v[CH];
#pragma unroll
    for (int ch = 0; ch < CH; ++ch) {
      const int b = ch * 64 + lane;
      v[ch] = (b < EB) ? bhT[wave * EB + b] : 0;
    }
    {
      int sum = 0;
#pragma unroll
      for (int ch = 0; ch < CH; ++ch) sum += v[ch];
#pragma unroll
      for (int off = 32; off > 0; off >>= 1) sum += __shfl_down(sum, off);
      if (lane == 0) tot_s[wave] = sum;
    }
    __syncthreads();
    if (threadIdx.x == 0) {
      int t = 0;
      for (int c = 0; c < 16; ++c) {
        ofs_s[c] = t;
        t += ((tot_s[c] + CHUNK - 1) / CHUNK) * CHUNK;
      }
    }
    __syncthreads();
    {  // chunk -> cell map; padding chunks get -1
      const int nch = (tot_s[wave] + CHUNK - 1) / CHUNK;
      const int cb = ofs_s[wave] / CHUNK;
      for (int i = lane; i < nch; i += 64) chunkcell[cb + i] = wave;
      if (wave == 15) {
        const int totch = cb + nch;
        for (int i = totch + lane; i < NBLK_EDGE; i += 64) chunkcell[i] = -1;
      }
    }
    {  // pad sentinels for this cell's segment
      const int startp = ofs_s[wave] + tot_s[wave];
      const int endp = ofs_s[wave] + ((tot_s[wave] + CHUNK - 1) / CHUNK) * CHUNK;
      for (int p = startp + lane; p < endp; p += 64) posrcS[p] = make_int2(-1, 0);
    }
    int running = ofs_s[wave];
#pragma unroll
    for (int ch = 0; ch < CH; ++ch) {
      int inc = v[ch];
#pragma unroll
      for (int off = 1; off < 64; off <<= 1) {
        int n = __shfl_up(inc, off);
        if (lane >= off) inc += n;
      }
      const int b = ch * 64 + lane;
      if (b < EB) blkbaseT[wave * EB + b] = running + inc - v[ch];
      running += __shfl(inc, 63);
    }
  } else {
    constexpr int SEG = NN / 16;          // 3125
    constexpr int CH = (SEG + 63) / 64;   // 49
    __shared__ int wofs[16];
    const int nbase = wave * SEG;
    int v[CH];
#pragma unroll
    for (int ch = 0; ch < CH; ++ch) {
      const int i = ch * 64 + lane;
      v[ch] = (i < SEG) ? degi[nbase + i] : 0;
    }
    {
      int sum = 0;
#pragma unroll
      for (int ch = 0; ch < CH; ++ch) sum += v[ch];
#pragma unroll
      for (int off = 32; off > 0; off >>= 1) sum += __shfl_down(sum, off);
      if (lane == 0) wofs[wave] = sum;
    }
    __syncthreads();
    if (threadIdx.x == 0) {
      int t = 0;
      for (int w2 = 0; w2 < 16; ++w2) { int tv = wofs[w2]; wofs[w2] = t; t += tv; }
    }
    __syncthreads();
    int running = wofs[wave];
#pragma unroll
    for (int ch = 0; ch < CH; ++ch) {
      int inc = v[ch];
#pragma unroll
      for (int off = 1; off < 64; off <<= 1) {
        int n = __shfl_up(inc, off);
        if (lane >= off) inc += n;
      }
      const int i = ch * 64 + lane;
      if (i < SEG) dstbase[nbase + i] = running + inc - v[ch];
      running += __shfl(inc, 63);
    }
  }
}

// Deterministic cell-sorted scatter; basis from attr; pos = dstbase + rankE.
__global__ __launch_bounds__(256) void scatter_edges(
    const float* __restrict__ attr, const int* __restrict__ blkbaseT,
    const int* __restrict__ srcArr, const int* __restrict__ dstArr,
    const int* __restrict__ rankE, const int* __restrict__ dstbase,
    int2* __restrict__ posrcS, f16x4* __restrict__ basS) {
  __shared__ int wc[4][16];
  __shared__ int bs[4][16];
  const int tid = threadIdx.x;
  const int e = blockIdx.x * 256 + tid;
  const float v0 = attr[2 * e] * 4.0f, v1 = attr[2 * e + 1] * 4.0f;
  const float fl0 = floorf(v0), fl1 = floorf(v1);
  const float fr0 = v0 - fl0, fr1 = v1 - fl1;
  const int bx = min(max((int)fl0, 0), 3);
  const int by = min(max((int)fl1, 0), 3);
  const int c = bx + 4 * by;
  const f16x4 bq = {(_Float16)((1.0f - fr0) * (1.0f - fr1)),
                    (_Float16)(fr0 * (1.0f - fr1)),
                    (_Float16)((1.0f - fr0) * fr1),
                    (_Float16)(fr0 * fr1)};
  const int wave = tid >> 6, lane = tid & 63;
  int rank = 0;
#pragma unroll
  for (int k = 0; k < 16; ++k) {
    unsigned long long mm = __ballot(c == k);
    if (k == c) rank = __popcll(mm & ((1ull << lane) - 1ull));
    if (lane == k) wc[wave][k] = __popcll(mm);
  }
  const int mypos = dstbase[dstArr[e]] + rankE[e];
  __syncthreads();
  if (tid < 16) {
    int running = blkbaseT[tid * EB + blockIdx.x];
#pragma unroll
    for (int w = 0; w < 4; ++w) { bs[w][tid] = running; running += wc[w][tid]; }
  }
  __syncthreads();
  const int p = bs[wave][c] + rank;
  posrcS[p] = make_int2(srcArr[e], mypos);
  basS[p] = bq;
}

// ------------------------------------------------- edge msg + root GEMM
// Edge role inner loop: per (ks,nt) ONE B ds_read feeds 4 MFMAs (4 M-tiles).
template <int IN, bool TWOPASS>
__global__ __launch_bounds__(256) void edge_root(
    const _Float16* __restrict__ xh, const _Float16* __restrict__ wcell,
    const int* __restrict__ chunkcell,
    const int2* __restrict__ posrcS, const f16x4* __restrict__ basS,
    const _Float16* __restrict__ rootT, const float* __restrict__ bias,
    _Float16* __restrict__ rth,
    unsigned char* __restrict__ msg, float* __restrict__ agg) {
  constexpr int K = 4 * IN;
  constexpr int KSTEPS = K / 32;
  constexpr int RS = K * 2;            // LDS row stride bytes
  constexpr int OPR = K / 8;           // 16B chunks per row
  constexpr int TILES = CHUNK / 64;    // 4
  constexpr int NCH = (IN == 64) ? 2 : 1;
  __shared__ f16x8 Wt[64 * OPR];
  const int tid = threadIdx.x;
  const int lane = tid & 63;
  const int wave = tid >> 6;
  const int g = lane >> 4, m = lane & 15;
  if (blockIdx.x >= NBLK_EDGE) {       // ---- root GEMM role ----
    constexpr int KS = IN / 32;
    const int base = (blockIdx.x - NBLK_EDGE) * 64 + wave * 16;
    if (base >= NN) return;
    f16x8 bf[KS][4];
#pragma unroll
    for (int ks = 0; ks < KS; ++ks)
#pragma unroll
      for (int nt = 0; nt < 4; ++nt)
        bf[ks][nt] = *reinterpret_cast<const f16x8*>(
            rootT + (size_t)(nt * 16 + m) * IN + ks * 32 + g * 8);
    const int row = base + m;
    f16x8 a[KS];
#pragma unroll
    for (int ks = 0; ks < KS; ++ks)
      a[ks] = *reinterpret_cast<const f16x8*>(xh + (size_t)row * IN + ks * 32 + g * 8);
    f32x4 acc[4];
#pragma unroll
    for (int nt = 0; nt < 4; ++nt) {
      const float fv = bias[nt * 16 + m];
      acc[nt] = (f32x4){fv, fv, fv, fv};
    }
#pragma unroll
    for (int ks = 0; ks < KS; ++ks)
#pragma unroll
      for (int nt = 0; nt < 4; ++nt)
        acc[nt] = __builtin_amdgcn_mfma_f32_16x16x32_f16(a[ks], bf[ks][nt], acc[nt], 0, 0, 0);
#pragma unroll
    for (int r = 0; r < 4; ++r) {
      const int node = base + g * 4 + r;
      f16x4 pv = {(_Float16)acc[0][r], (_Float16)acc[1][r],
                  (_Float16)acc[2][r], (_Float16)acc[3][r]};
      *reinterpret_cast<f16x4*>(rth + (size_t)node * 64 + m * 4) = pv;
    }
    return;
  }
  // ---- edge transform role ----
  const int c = chunkcell[blockIdx.x];
  if (c < 0) return;                   // fully-padded chunk
  const int base = blockIdx.x * CHUNK;
  const int wbase = base + wave * (CHUNK / 4);
  int2 sp_t[TILES];
  f16x4 bas_t[TILES];
#pragma unroll
  for (int t = 0; t < TILES; ++t) sp_t[t] = posrcS[wbase + t * 16 + m];
#pragma unroll
  for (int t = 0; t < TILES; ++t) bas_t[t] = basS[wbase + t * 16 + m];
  {
    const f16x8* gw = reinterpret_cast<const f16x8*>(wcell) + (size_t)c * (64 * OPR);
    for (int o = tid; o < 64 * OPR; o += 256) Wt[o] = gw[o];
  }
  __syncthreads();
  f16x8 xc[TILES][NCH];
#pragma unroll
  for (int t = 0; t < TILES; ++t) {
    const int row = (sp_t[t].x >= 0) ? sp_t[t].x : 0;
    const f16x8* xr = reinterpret_cast<const f16x8*>(xh + (size_t)row * IN);
    xc[t][0] = xr[g];
    if constexpr (IN == 64) xc[t][1] = xr[4 + g];
  }
  // All 4 tiles accumulated together; B read once per (ks,nt).
  f32x4 acc[TILES][4];
#pragma unroll
  for (int t = 0; t < TILES; ++t)
#pragma unroll
    for (int nt = 0; nt < 4; ++nt) acc[t][nt] = (f32x4){0.f, 0.f, 0.f, 0.f};
#pragma unroll
  for (int ks = 0; ks < KSTEPS; ++ks) {
    const int s = (IN == 64) ? (ks & 3) : ks;
    f16x8 a[TILES];
#pragma unroll
    for (int t = 0; t < TILES; ++t) {
      const f16x8 xin = (IN == 64 && (ks >> 2)) ? xc[t][1] : xc[t][0];
      a[t] = xin * bas_t[t][s];
    }
#pragma unroll
    for (int nt = 0; nt < 4; ++nt) {
      const int n = nt * 16 + m;
      const int byte = n * RS + (((ks * 64) + g * 16) ^ ((n & 15) << 4));
      const f16x8 bfrag = Wt[byte >> 4];   // ONE LDS read -> 4 MFMAs
#pragma unroll
      for (int t = 0; t < TILES; ++t)
        acc[t][nt] = __builtin_amdgcn_mfma_f32_16x16x32_f16(a[t], bfrag, acc[t][nt], 0, 0, 0);
    }
  }
  // epilogue: D row = edge (lane>>4)*4+r, D col = nt*16 + (lane&15).
#pragma unroll
  for (int t = 0; t < TILES; ++t) {
#pragma unroll
    for (int r = 0; r < 4; ++r) {
      const int m2 = g * 4 + r;
      const int er = __shfl(sp_t[t].x, m2);
      const int pr = __shfl(sp_t[t].y, m2);
      if (er >= 0) {
        if constexpr (TWOPASS) {
          unsigned int p8 = __builtin_amdgcn_cvt_pk_fp8_f32(acc[t][0][r], acc[t][1][r], 0u, false);
          p8 = __builtin_amdgcn_cvt_pk_fp8_f32(acc[t][2][r], acc[t][3][r], p8, true);
          *reinterpret_cast<unsigned int*>(msg + (size_t)pr * 64 + m * 4) = p8;
        } else {
          float* ap = agg + (size_t)pr * 64 + m;
#pragma unroll
          for (int nt = 0; nt < 4; ++nt) atomicAdd(ap + nt * 16, acc[t][nt][r]);
        }
      }
    }
  }
}

// --------------------------------------------------------------- pass2
// Pure segment-reduce over fp8 msg: xh_out = relu(mean + rt). No LDS/sync.
__global__ __launch_bounds__(256) void pass2_kernel(
    const unsigned char* __restrict__ msg, const int* __restrict__ dstbase,
    const int* __restrict__ degi, const _Float16* __restrict__ rth,
    _Float16* __restrict__ xh_out) {
  const int wave = threadIdx.x >> 6, lane = threadIdx.x & 63;
  const int n = blockIdx.x * 4 + wave;   // grid sized so n < NN always
  const int q = lane >> 4, m = lane & 15;
  const _Float16 rv = rth[(size_t)n * 64 + m * 4 + q];  // channel q*16+m
  const int b0 = dstbase[n], dg = degi[n];
  const unsigned int* mp =
      reinterpret_cast<const unsigned int*>(msg + (size_t)b0 * 64 + m * 4);
  float a0 = 0.f, a1 = 0.f, a2 = 0.f, a3 = 0.f;
  const int nfull = dg & ~15;
  int j0 = 0;
  for (; j0 < nfull; j0 += 16) {
    const unsigned int* bp = mp + (size_t)j0 * 16;   // row stride = 16 uints
#pragma unroll
    for (int u = 0; u < 4; ++u) {
      const unsigned int pw = bp[(size_t)(u * 4 + q) * 16];
      const auto lo = __builtin_amdgcn_cvt_pk_f32_fp8(pw, false);
      const auto hi = __builtin_amdgcn_cvt_pk_f32_fp8(pw, true);
      a0 += lo[0]; a1 += lo[1]; a2 += hi[0]; a3 += hi[1];
    }
  }
  if (j0 < dg) {  // masked tail (<16 rows)
#pragma unroll
    for (int u = 0; u < 4; ++u) {
      const int jj = j0 + u * 4 + q;
      const int jc = min(jj, dg - 1);
      const unsigned int pw = mp[(size_t)jc * 16];
      const auto lo = __builtin_amdgcn_cvt_pk_f32_fp8(pw, false);
      const auto hi = __builtin_amdgcn_cvt_pk_f32_fp8(pw, true);
      const float wv = (jj < dg) ? 1.0f : 0.0f;
      a0 = fmaf(wv, lo[0], a0);
      a1 = fmaf(wv, lo[1], a1);
      a2 = fmaf(wv, hi[0], a2);
      a3 = fmaf(wv, hi[1], a3);
    }
  }
  a0 += __shfl_xor(a0, 16); a0 += __shfl_xor(a0, 32);
  a1 += __shfl_xor(a1, 16); a1 += __shfl_xor(a1, 32);
  a2 += __shfl_xor(a2, 16); a2 += __shfl_xor(a2, 32);
  a3 += __shfl_xor(a3, 16); a3 += __shfl_xor(a3, 32);
  const float acc = (q == 0) ? a0 : (q == 1) ? a1 : (q == 2) ? a2 : a3;
  const float r = fmaxf(acc / fmaxf((float)dg, 1.0f) + (float)rv, 0.0f);
  xh_out[(size_t)n * 64 + lane] = (_Float16)r;   // lane == channel q*16+m
}

// --------------------------------------------------------------- finalize
// (atomic-fallback path only)
template <int IN>
__global__ __launch_bounds__(256) void finalize_kernel(
    const _Float16* __restrict__ xh_in, const float* __restrict__ agg,
    const int* __restrict__ degi, const float* __restrict__ root,
    const float* __restrict__ bias, _Float16* __restrict__ xh_out) {
  __shared__ float rl[IN * 64];
  for (int idx = threadIdx.x; idx < IN * 16; idx += 256)
    reinterpret_cast<float4*>(rl)[idx] = reinterpret_cast<const float4*>(root)[idx];
  __syncthreads();
  const int wave = threadIdx.x >> 6, lane = threadIdx.x & 63;
  const int n = blockIdx.x * 4 + wave;
  if (n >= NN) return;
  const float d = fmaxf((float)degi[n], 1.0f);
  float r = agg[(size_t)n * 64 + lane] / d + bias[lane];
  const _Float16* xr = xh_in + (size_t)n * IN;
#pragma unroll 8
  for (int i = 0; i < IN; ++i) r = fmaf((float)xr[i], rl[i * 64 + lane], r);
  r = fmaxf(r, 0.0f);
  xh_out[(size_t)n * 64 + lane] = (_Float16)r;
}

// ------------------------------------------------------------------- output
__global__ __launch_bounds__(256) void out_mfma(
    const _Float16* __restrict__ xh0, const _Float16* __restrict__ xh1,
    const _Float16* __restrict__ xh2, const _Float16* __restrict__ fwT,
    const float* __restrict__ fb, float* __restrict__ out) {
  const int lane = threadIdx.x & 63, wave = threadIdx.x >> 6;
  const int g = lane >> 4, m = lane & 15;
  const int base = blockIdx.x * 64 + wave * 16;   // NN % 16 == 0
  if (base >= NN) return;
  f16x8 bf[5][4];
#pragma unroll
  for (int ks = 0; ks < 5; ++ks)
#pragma unroll
    for (int nt = 0; nt < 4; ++nt)
      bf[ks][nt] = *reinterpret_cast<const f16x8*>(
          fwT + (size_t)(nt * 16 + m) * 160 + ks * 32 + g * 8);
  const int row = base + m;
  f16x8 a[5];
  a[0] = *reinterpret_cast<const f16x8*>(xh0 + (size_t)row * 32 + g * 8);
  a[1] = *reinterpret_cast<const f16x8*>(xh1 + (size_t)row * 64 + g * 8);
  a[2] = *reinterpret_cast<const f16x8*>(xh1 + (size_t)row * 64 + 32 + g * 8);
  a[3] = *reinterpret_cast<const f16x8*>(xh2 + (size_t)row * 64 + g * 8);
  a[4] = *reinterpret_cast<const f16x8*>(xh2 + (size_t)row * 64 + 32 + g * 8);
  f32x4 acc[4];
#pragma unroll
  for (int nt = 0; nt < 4; ++nt) {
    const float fv = fb[nt * 16 + m];
    acc[nt] = (f32x4){fv, fv, fv, fv};
  }
#pragma unroll
  for (int ks = 0; ks < 5; ++ks)
#pragma unroll
    for (int nt = 0; nt < 4; ++nt)
      acc[nt] = __builtin_amdgcn_mfma_f32_16x16x32_f16(a[ks], bf[ks][nt], acc[nt], 0, 0, 0);
#pragma unroll
  for (int r = 0; r < 4; ++r) {
    float* op = out + (size_t)(base + g * 4 + r) * 64 + m;
#pragma unroll
    for (int nt = 0; nt < 4; ++nt) op[nt * 16] = acc[nt][r];
  }
}

extern "C" void kernel_launch(void* const* d_in, const int* in_sizes, int n_in,
                              void* d_out, int out_size, void* d_ws, size_t ws_size,
                              hipStream_t stream) {
  const float* x0 = (const float*)d_in[0];
  const void* eidx = d_in[1];
  const float* attr = (const float*)d_in[2];
  const float* w0 = (const float*)d_in[3];
  const float* root0 = (const float*)d_in[4];
  const float* b0 = (const float*)d_in[5];
  const float* w1 = (const float*)d_in[6];
  const float* root1 = (const float*)d_in[7];
  const float* b1 = (const float*)d_in[8];
  const float* fw = (const float*)d_in[9];
  const float* fb = (const float*)d_in[10];
  float* out = (float*)d_out;
  (void)in_sizes; (void)n_in; (void)out_size;

  char* wsb = (char*)d_ws;
  size_t off = 0;
  auto alloc = [&](size_t bytes) -> void* {
    void* p = wsb + off;
    off += (bytes + 255) & ~(size_t)255;
    return p;
  };
  int* flag = (int*)alloc(256);
  int* src = (int*)alloc(sizeof(int) * EE);
  int* dst = (int*)alloc(sizeof(int) * EE);
  int* rankE = (int*)alloc(sizeof(int) * EE);
  int2* posrcS = (int2*)alloc(sizeof(int2) * ELIST_LEN);
  f16x4* basS = (f16x4*)alloc(sizeof(f16x4) * ELIST_LEN);
  int* chunkcell = (int*)alloc(sizeof(int) * NBLK_EDGE);
  int* degi = (int*)alloc(sizeof(int) * NN);
  int* dstbase = (int*)alloc(sizeof(int) * NN);
  int* bhT = (int*)alloc(sizeof(int) * EB * 16);
  int* blkbaseT = (int*)alloc(sizeof(int) * EB * 16);
  _Float16* xh0 = (_Float16*)alloc(sizeof(_Float16) * NN * 32);
  _Float16* xh1 = (_Float16*)alloc(sizeof(_Float16) * NN * 64);
  _Float16* xh2 = (_Float16*)alloc(sizeof(_Float16) * NN * 64);
  _Float16* rth = (_Float16*)alloc(sizeof(_Float16) * NN * 64);
  _Float16* wc0 = (_Float16*)alloc(sizeof(_Float16) * 16 * 128 * 64);  // 256KB
  _Float16* wc1 = (_Float16*)alloc(sizeof(_Float16) * 16 * 256 * 64);  // 512KB
  _Float16* fwT = (_Float16*)alloc(sizeof(_Float16) * 64 * 160);
  _Float16* rt0T = (_Float16*)alloc(sizeof(_Float16) * 64 * 32);
  _Float16* rt1T = (_Float16*)alloc(sizeof(_Float16) * 64 * 64);
  const size_t common = off;
  const bool twopass = ws_size >= common + (size_t)EE * 64;  // fp8 msg: 51.2MB
  unsigned char* msg = nullptr;
  float* agg = nullptr;
  if (twopass) msg = (unsigned char*)alloc((size_t)EE * 64);
  else         agg = (float*)alloc(sizeof(float) * (size_t)NN * 64);

  detect_init<<<(NN + 255) / 256, 256, 0, stream>>>(
      (const long long*)eidx, flag, degi);
  prep_conv<<<EB + CONV_BLK, 256, 0, stream>>>(
      eidx, attr, flag, src, dst, rankE, degi, bhT,
      x0, w0, w1, fw, root0, root1, xh0, wc0, wc1, fwT, rt0T, rt1T);
  scan_fused<<<2, 1024, 0, stream>>>(bhT, blkbaseT, chunkcell, posrcS, degi, dstbase);
  scatter_edges<<<EB, 256, 0, stream>>>(attr, blkbaseT, src, dst, rankE, dstbase,
                                        posrcS, basS);

  if (twopass) {
    edge_root<32, true><<<NBLK_EDGE + RT_BLK, 256, 0, stream>>>(
        xh0, wc0, chunkcell, posrcS, basS, rt0T, b0, rth, msg, nullptr);
    pass2_kernel<<<NN / 4, 256, 0, stream>>>(msg, dstbase, degi, rth, xh1);
    edge_root<64, true><<<NBLK_EDGE + RT_BLK, 256, 0, stream>>>(
        xh1, wc1, chunkcell, posrcS, basS, rt1T, b1, rth, msg, nullptr);
    pass2_kernel<<<NN / 4, 256, 0, stream>>>(msg, dstbase, degi, rth, xh2);
  } else {
    hipMemsetAsync(agg, 0, sizeof(float) * NN * 64, stream);
    edge_root<32, false><<<NBLK_EDGE, 256, 0, stream>>>(
        xh0, wc0, chunkcell, posrcS, basS, rt0T, b0, rth, nullptr, agg);
    finalize_kernel<32><<<(NN + 3) / 4, 256, 0, stream>>>(xh0, agg, degi, root0, b0, xh1);
    hipMemsetAsync(agg, 0, sizeof(float) * NN * 64, stream);
    edge_root<64, false><<<NBLK_EDGE, 256, 0, stream>>>(
        xh1, wc1, chunkcell, posrcS, basS, rt1T, b1, rth, nullptr, agg);
    finalize_kernel<64><<<(NN + 3) / 4, 256, 0, stream>>>(xh1, agg, degi, root1, b1, xh2);
  }

  out_mfma<<<(NN + 63) / 64, 256, 0, stream>>>(xh0, xh1, xh2, fwT, fb, out);
}